// Round 7
// baseline (383.529 us; speedup 1.0000x reference)
//
#include <hip/hip_runtime.h>
#include <math.h>

#define BB 16384
#define HH 512

typedef short short8 __attribute__((ext_vector_type(8)));
typedef float f32x4 __attribute__((ext_vector_type(4)));
typedef unsigned short ushort_t;

__device__ __forceinline__ float sigm(float v){ return 1.0f/(1.0f+expf(-v)); }

__device__ __forceinline__ unsigned short f2bf(float f){
    unsigned int u = __float_as_uint(f);
    u = u + 0x7FFFu + ((u>>16)&1u);
    return (unsigned short)(u>>16);
}
__device__ __forceinline__ float bf2f(unsigned short h){
    return __uint_as_float(((unsigned int)h)<<16);
}
__device__ __forceinline__ void gll16(const void* g, void* l){
    __builtin_amdgcn_global_load_lds((const __attribute__((address_space(1))) void*)g,
                                     (__attribute__((address_space(3))) void*)l, 16, 0, 0);
}
__device__ __forceinline__ void split_store(float v, ushort_t* ph, ushort_t* pl, int j){
    unsigned short h = f2bf(v);
    unsigned short l = f2bf(v - bf2f(h));
    ph[j] = h; pl[j] = l;
}

// ---------------- merged prepass ----------------
// A1: fragment-order layout. Per (tm [128-row tile], u [K32 step]) block of 4096
// elems: [lq(4)][f(8)][l15(16)][j(8)] -> lane (lq,l15) frag f loads 16B direct.
// A2: same fragment layout, tiles tk 0..15 filled from c0 (hi half by gates epi).
// B1/B2: unchanged LDS-staging layouts [tile][c][col][8].
__global__ void k_prep_all(
    const float* __restrict__ x, const float* __restrict__ h0, const float* __restrict__ c0,
    const float* __restrict__ W_ih, const float* __restrict__ W_hh,
    const float* __restrict__ b_ih, const float* __restrict__ b_hh,
    const float* __restrict__ W_sp, const float* __restrict__ W_sc, const float* __restrict__ W_tp,
    const float* __restrict__ b_sp, const float* __restrict__ b_sc, const float* __restrict__ b_tp,
    ushort_t* __restrict__ A1h, ushort_t* __restrict__ A1l,
    ushort_t* __restrict__ A2h, ushort_t* __restrict__ A2l,
    ushort_t* __restrict__ B1h, ushort_t* __restrict__ B1l,
    ushort_t* __restrict__ B2h, ushort_t* __restrict__ B2l,
    float* __restrict__ bgp, float* __restrict__ bs2)
{
    int bid = blockIdx.x;
    if (bid < 8192) {
        int u = bid*256 + threadIdx.x;             // 2^21 units
        int tm  = u >> 14;
        int rem = u & 16383;
        int kt  = rem >> 9;
        int lq  = (rem >> 7) & 3;
        int f   = (rem >> 4) & 7;
        int l15 = rem & 15;
        int row = tm*128 + f*16 + l15;
        int k0  = kt*32 + lq*8;
        const float* src = (k0 < 512) ? (x + (size_t)row*512 + k0)
                                      : (h0 + (size_t)row*512 + (k0-512));
        float4 v0 = *(const float4*)(src);
        float4 v1 = *(const float4*)(src+4);
        float vv[8] = {v0.x,v0.y,v0.z,v0.w,v1.x,v1.y,v1.z,v1.w};
        size_t off = (size_t)u * 8;
#pragma unroll
        for (int j=0;j<8;++j) split_store(vv[j], A1h+off, A1l+off, j);
    } else if (bid < 12288) {
        int u = (bid-8192)*256 + threadIdx.x;      // 2^20 units
        int tm  = u >> 13;
        int rem = u & 8191;
        int kt  = rem >> 9;                        // 0..15
        int lq  = (rem >> 7) & 3;
        int f   = (rem >> 4) & 7;
        int l15 = rem & 15;
        int row = tm*128 + f*16 + l15;
        int k0  = kt*32 + lq*8;
        const float* src = c0 + (size_t)row*512 + k0;
        float4 v0 = *(const float4*)(src);
        float4 v1 = *(const float4*)(src+4);
        float vv[8] = {v0.x,v0.y,v0.z,v0.w,v1.x,v1.y,v1.z,v1.w};
        size_t off = ((size_t)tm*32 + kt)*4096 + (size_t)(rem & 511)*8;
#pragma unroll
        for (int j=0;j<8;++j) split_store(vv[j], A2h+off, A2l+off, j);
    } else if (bid < 13312) {
        int u = (bid-12288)*256 + threadIdx.x;     // 262,144
        int r  = u & 255;
        int c  = (u >> 8) & 3;
        int kt = (u >> 10) & 31;
        int tn = u >> 15;
        int g = (r>>4)&3;
        int h = tn*64 + (r>>6)*16 + (r&15);
        int wrow = g*512 + h;
        int k0 = kt*32 + c*8;
        const float* src = (k0 < 512) ? (W_ih + (size_t)wrow*512 + k0)
                                      : (W_hh + (size_t)wrow*512 + (k0-512));
        float4 v0 = *(const float4*)(src);
        float4 v1 = *(const float4*)(src+4);
        float vv[8] = {v0.x,v0.y,v0.z,v0.w,v1.x,v1.y,v1.z,v1.w};
        size_t off = (size_t)u * 8;
#pragma unroll
        for (int j=0;j<8;++j) split_store(vv[j], B1h+off, B1l+off, j);
        if (kt == 0 && c == 0) bgp[tn*256 + r] = b_ih[wrow] + b_hh[wrow];
    } else {
        int u = (bid-13312)*256 + threadIdx.x;     // 65,536
        int r  = u & 127;
        int c  = (u >> 7) & 3;
        int tk = (u >> 9) & 31;
        int tn = u >> 14;
        int n = tn*128 + r;
        int k0 = tk*32 + c*8;
        float vv[8];
        if (n < 256) {
            const float* src = (k0 < 512) ? (W_sp + (size_t)n*512 + k0)
                                          : (W_sc + (size_t)n*512 + (k0-512));
            float4 v0 = *(const float4*)(src);
            float4 v1 = *(const float4*)(src+4);
            vv[0]=v0.x; vv[1]=v0.y; vv[2]=v0.z; vv[3]=v0.w;
            vv[4]=v1.x; vv[5]=v1.y; vv[6]=v1.z; vv[7]=v1.w;
        } else if (k0 < 512) {
            const float* src = W_tp + (size_t)(n-256)*512 + k0;
            float4 v0 = *(const float4*)(src);
            float4 v1 = *(const float4*)(src+4);
            vv[0]=v0.x; vv[1]=v0.y; vv[2]=v0.z; vv[3]=v0.w;
            vv[4]=v1.x; vv[5]=v1.y; vv[6]=v1.z; vv[7]=v1.w;
        } else {
#pragma unroll
            for (int j=0;j<8;++j) vv[j] = 0.0f;
        }
        size_t off = (size_t)u * 8;
#pragma unroll
        for (int j=0;j<8;++j) split_store(vv[j], B2h+off, B2l+off, j);
        if (tk == 0 && c == 0) bs2[n] = (n < 256) ? (b_sp[n] + b_sc[n]) : b_tp[n-256];
    }
}

// ---------- GEMM1: gates, 128x256 tile, A from GLOBAL regs, B via LDS ----------
// K-steps 0-31: Ah*Bh ; 32-63: Al*Bh ; 64-95: Ah*Bl
// Per step T: load A-frags(T+1)->regs, stage B(T+3)->LDS (4-deep), ds_read
// B-frags(T+1), MFMA(T), vmcnt(4)+lgkm(0), barrier.
#define GSTEP(T, CA, CB, NA, NB, DO_A, DO_BSTAGE, DO_BREAD, WAITASM)                 \
  {                                                                                  \
    if (DO_A) {                                                                      \
        const int un = (T) + 1;                                                      \
        const ushort_t* As_ = ((un >> 5) == 1) ? Al : Ah;                            \
        const ushort_t* ap = As_ + ((size_t)tm*32 + (un & 31))*4096 + aG;            \
        _Pragma("unroll") for (int f = 0; f < 8; ++f)                                \
            NA[f] = *(const short8*)(ap + f*128);                                    \
    }                                                                                \
    if (DO_BSTAGE) {                                                                 \
        const int uu = (T) + 3;                                                      \
        const ushort_t* Bs_ = ((uu >> 5) == 2) ? Bl : Bh;                            \
        const ushort_t* gB = Bs_ + ((size_t)tn*32 + (uu & 31))*8192;                 \
        ushort_t* dB = &ldsB[uu & 3][0];                                             \
        _Pragma("unroll") for (int q = 0; q < 4; ++q)                                \
            gll16(gB + (q*256 + tid)*8, dB + (q*256 + tid)*8);                       \
    }                                                                                \
    if (DO_BREAD) {                                                                  \
        const ushort_t* bB = &ldsB[((T)+1) & 3][0];                                  \
        _Pragma("unroll") for (int fn = 0; fn < 4; ++fn)                             \
            NB[fn] = *(const short8*)&bB[boff[fn]];                                  \
    }                                                                                \
    __builtin_amdgcn_s_setprio(1);                                                   \
    _Pragma("unroll") for (int fm = 0; fm < 8; ++fm)                                 \
        _Pragma("unroll") for (int fn = 0; fn < 4; ++fn)                             \
            acc[fm][fn] = __builtin_amdgcn_mfma_f32_16x16x32_bf16(CA[fm], CB[fn], acc[fm][fn], 0,0,0); \
    __builtin_amdgcn_s_setprio(0);                                                   \
    __builtin_amdgcn_sched_barrier(0);                                               \
    WAITASM;                                                                         \
    __builtin_amdgcn_sched_barrier(0);                                               \
    asm volatile("s_barrier" ::: "memory");                                          \
  }

__global__ __launch_bounds__(256, 2) void k_gemm_gates(
    const ushort_t* __restrict__ Ah, const ushort_t* __restrict__ Al,
    const ushort_t* __restrict__ Bh, const ushort_t* __restrict__ Bl,
    const float* __restrict__ bgp, const float* __restrict__ c0,
    float* __restrict__ outH, float* __restrict__ outC,
    ushort_t* __restrict__ A2h, ushort_t* __restrict__ A2l)
{
    __shared__ __align__(16) ushort_t ldsB[4][8192];   // 64 KiB (B only, 4-deep)
    const int tid  = threadIdx.x;
    const int lane = tid & 63;
    const int wc   = tid >> 6;        // 0..3 -> cols wc*16 within 64-h group
    const int l15  = lane & 15;
    const int lq   = lane >> 4;
    const int bid  = (int)blockIdx.x;
    const int v    = (bid & 7)*128 + (bid >> 3);   // XCD swizzle (1024 blocks)
    const int tm   = v >> 3;          // 0..127 (128-row tiles)
    const int tn   = v & 7;           // 0..7   (256-gatecol tiles)
    const int aG   = lq*1024 + l15*8;

    f32x4 acc[8][4];
#pragma unroll
    for (int fn = 0; fn < 4; ++fn) {
        float bv = bgp[tn*256 + wc*64 + fn*16 + l15];
#pragma unroll
        for (int fm = 0; fm < 8; ++fm) {
            acc[fm][fn][0]=bv; acc[fm][fn][1]=bv; acc[fm][fn][2]=bv; acc[fm][fn][3]=bv;
        }
    }

    int boff[4];
#pragma unroll
    for (int f = 0; f < 4; ++f) boff[f] = (lq*256 + wc*64 + f*16 + l15) * 8;

    short8 a0[8], b0[4], a1[8], b1[4];

    // prologue: A(0)->regs, stage B(0..2); drain A0,B0,B1 (leave B2); read B0 frags
    {
        const ushort_t* ap0 = Ah + (size_t)tm*32*4096 + aG;
#pragma unroll
        for (int f = 0; f < 8; ++f) a0[f] = *(const short8*)(ap0 + f*128);
#pragma unroll
        for (int u0 = 0; u0 < 3; ++u0) {
            const ushort_t* gB = Bh + ((size_t)tn*32 + u0)*8192;
#pragma unroll
            for (int q = 0; q < 4; ++q)
                gll16(gB + (q*256 + tid)*8, &ldsB[u0][(q*256 + tid)*8]);
        }
    }
    asm volatile("s_waitcnt vmcnt(4)" ::: "memory");
    asm volatile("s_barrier" ::: "memory");
#pragma unroll
    for (int f = 0; f < 4; ++f) b0[f] = *(const short8*)&ldsB[0][boff[f]];
    asm volatile("s_waitcnt lgkmcnt(0)" ::: "memory");
    __builtin_amdgcn_sched_barrier(0);

    for (int t = 0; t < 92; t += 2) {
        GSTEP(t,   a0,b0, a1,b1, 1,1,1, asm volatile("s_waitcnt vmcnt(4) lgkmcnt(0)" ::: "memory"));
        GSTEP(t+1, a1,b1, a0,b0, 1,1,1, asm volatile("s_waitcnt vmcnt(4) lgkmcnt(0)" ::: "memory"));
    }
    GSTEP(92, a0,b0, a1,b1, 1,1,1, asm volatile("s_waitcnt vmcnt(4) lgkmcnt(0)" ::: "memory"));
    GSTEP(93, a1,b1, a0,b0, 1,0,1, asm volatile("s_waitcnt vmcnt(0) lgkmcnt(0)" ::: "memory"));
    GSTEP(94, a0,b0, a1,b1, 1,0,1, asm volatile("s_waitcnt vmcnt(0) lgkmcnt(0)" ::: "memory"));
    GSTEP(95, a1,b1, a0,b0, 0,0,0, ((void)0));

    // epilogue: lane holds 4 gates (fn) for rows lq*4+r, col h
    const int h = tn*64 + wc*16 + l15;
#pragma unroll
    for (int fm = 0; fm < 8; ++fm) {
        int row0 = tm*128 + fm*16 + lq*4;
#pragma unroll
        for (int r = 0; r < 4; ++r) {
            int row = row0 + r;
            size_t idx = (size_t)row*512 + h;
            float ig = sigm(acc[fm][0][r]);
            float fg = sigm(acc[fm][1][r]);
            float gg = tanhf(acc[fm][2][r]);
            float og = sigm(acc[fm][3][r]);
            float c1 = fg*c0[idx] + ig*gg;
            float h1 = og*tanhf(c1);
            outC[idx] = c1;
            outH[idx] = h1;
            unsigned short ch = f2bf(c1);
            unsigned short cl = f2bf(c1 - bf2f(ch));
            // A2 fragment layout: (tm2, u=16+(h>>5)) block; [lq=(h>>3)&3][f=(row&127)>>4][l15=row&15][j=h&7]
            size_t a2 = ((size_t)(row>>7)*32 + 16 + (h>>5))*4096
                      + (size_t)((h>>3)&3)*1024 + (size_t)(((row&127)>>4))*128
                      + (size_t)(row&15)*8 + (h&7);
            A2h[a2] = ch;
            A2l[a2] = cl;
        }
    }
}

// ---------- GEMM2: sg|tg, 128x128 tile, same A-reg/B-LDS structure ----------
#define SSTEP(T, CA, CB, NA, NB, DO_A, DO_BSTAGE, DO_BREAD, WAITASM)                 \
  {                                                                                  \
    if (DO_A) {                                                                      \
        const int un = (T) + 1;                                                      \
        const ushort_t* As_ = ((un >> 5) == 1) ? Al : Ah;                            \
        const ushort_t* ap = As_ + ((size_t)tm*32 + (un & 31))*4096 + aG;            \
        _Pragma("unroll") for (int f = 0; f < 8; ++f)                                \
            NA[f] = *(const short8*)(ap + f*128);                                    \
    }                                                                                \
    if (DO_BSTAGE) {                                                                 \
        const int uu = (T) + 3;                                                      \
        const ushort_t* Bs_ = ((uu >> 5) == 2) ? Bl : Bh;                            \
        const ushort_t* gB = Bs_ + ((size_t)tn*32 + (uu & 31))*4096;                 \
        ushort_t* dB = &ldsB2[uu & 3][0];                                            \
        _Pragma("unroll") for (int q = 0; q < 2; ++q)                                \
            gll16(gB + (q*256 + tid)*8, dB + (q*256 + tid)*8);                       \
    }                                                                                \
    if (DO_BREAD) {                                                                  \
        const ushort_t* bB = &ldsB2[((T)+1) & 3][0];                                 \
        _Pragma("unroll") for (int fn = 0; fn < 2; ++fn)                             \
            NB[fn] = *(const short8*)&bB[boff2[fn]];                                 \
    }                                                                                \
    __builtin_amdgcn_s_setprio(1);                                                   \
    _Pragma("unroll") for (int fm = 0; fm < 8; ++fm)                                 \
        _Pragma("unroll") for (int fn = 0; fn < 2; ++fn)                             \
            acc[fm][fn] = __builtin_amdgcn_mfma_f32_16x16x32_bf16(CA[fm], CB[fn], acc[fm][fn], 0,0,0); \
    __builtin_amdgcn_s_setprio(0);                                                   \
    __builtin_amdgcn_sched_barrier(0);                                               \
    WAITASM;                                                                         \
    __builtin_amdgcn_sched_barrier(0);                                               \
    asm volatile("s_barrier" ::: "memory");                                          \
  }

__global__ __launch_bounds__(256, 3) void k_gemm_sgtg(
    const ushort_t* __restrict__ Ah, const ushort_t* __restrict__ Al,
    const ushort_t* __restrict__ Bh, const ushort_t* __restrict__ Bl,
    const float* __restrict__ bs2,
    float* __restrict__ sgtg)
{
    __shared__ __align__(16) ushort_t ldsB2[4][4096];   // 32 KiB
    const int tid  = threadIdx.x;
    const int lane = tid & 63;
    const int wc   = tid >> 6;        // 0..3 -> cols wc*32
    const int l15  = lane & 15;
    const int lq   = lane >> 4;
    const int bid  = (int)blockIdx.x;
    const int v    = (bid & 7)*64 + (bid >> 3);   // XCD swizzle (512 blocks)
    const int tm   = v >> 2;          // 0..127
    const int tn   = v & 3;           // 0..3
    const int aG   = lq*1024 + l15*8;

    f32x4 acc[8][2];
#pragma unroll
    for (int fn = 0; fn < 2; ++fn) {
        float bv = bs2[tn*128 + wc*32 + fn*16 + l15];
#pragma unroll
        for (int fm = 0; fm < 8; ++fm) {
            acc[fm][fn][0]=bv; acc[fm][fn][1]=bv; acc[fm][fn][2]=bv; acc[fm][fn][3]=bv;
        }
    }

    int boff2[2];
#pragma unroll
    for (int f = 0; f < 2; ++f) boff2[f] = (lq*128 + wc*32 + f*16 + l15) * 8;

    short8 a0[8], b0[2], a1[8], b1[2];

    {
        const ushort_t* ap0 = Ah + (size_t)tm*32*4096 + aG;
#pragma unroll
        for (int f = 0; f < 8; ++f) a0[f] = *(const short8*)(ap0 + f*128);
#pragma unroll
        for (int u0 = 0; u0 < 3; ++u0) {
            const ushort_t* gB = Bh + ((size_t)tn*32 + u0)*4096;
#pragma unroll
            for (int q = 0; q < 2; ++q)
                gll16(gB + (q*256 + tid)*8, &ldsB2[u0][(q*256 + tid)*8]);
        }
    }
    asm volatile("s_waitcnt vmcnt(2)" ::: "memory");
    asm volatile("s_barrier" ::: "memory");
#pragma unroll
    for (int f = 0; f < 2; ++f) b0[f] = *(const short8*)&ldsB2[0][boff2[f]];
    asm volatile("s_waitcnt lgkmcnt(0)" ::: "memory");
    __builtin_amdgcn_sched_barrier(0);

    for (int t = 0; t < 92; t += 2) {
        SSTEP(t,   a0,b0, a1,b1, 1,1,1, asm volatile("s_waitcnt vmcnt(2) lgkmcnt(0)" ::: "memory"));
        SSTEP(t+1, a1,b1, a0,b0, 1,1,1, asm volatile("s_waitcnt vmcnt(2) lgkmcnt(0)" ::: "memory"));
    }
    SSTEP(92, a0,b0, a1,b1, 1,1,1, asm volatile("s_waitcnt vmcnt(2) lgkmcnt(0)" ::: "memory"));
    SSTEP(93, a1,b1, a0,b0, 1,0,1, asm volatile("s_waitcnt vmcnt(0) lgkmcnt(0)" ::: "memory"));
    SSTEP(94, a0,b0, a1,b1, 1,0,1, asm volatile("s_waitcnt vmcnt(0) lgkmcnt(0)" ::: "memory"));
    SSTEP(95, a1,b1, a0,b0, 0,0,0, ((void)0));

#pragma unroll
    for (int fm = 0; fm < 8; ++fm) {
        int row0 = tm*128 + fm*16 + lq*4;
#pragma unroll
        for (int fn = 0; fn < 2; ++fn) {
            int n = tn*128 + wc*32 + fn*16 + l15;
#pragma unroll
            for (int r = 0; r < 4; ++r) {
                int row = row0 + r;
                float vv = acc[fm][fn][r];
                vv = vv > 0.f ? vv : 0.01f*vv;
                sgtg[(size_t)row*512 + n] = vv;
            }
        }
    }
}

// ---------- final: row dots, threshold decision, gated writeback ----------
__global__ __launch_bounds__(256) void k_final(
    const float* __restrict__ sgtg,
    const float* __restrict__ h0, const float* __restrict__ c0,
    const float* __restrict__ cum,
    const float* __restrict__ W_so, const float* __restrict__ b_so,
    const float* __restrict__ W_to, const float* __restrict__ b_to,
    float* __restrict__ outH, float* __restrict__ outC,
    float* __restrict__ outCum, float* __restrict__ outDelta, float* __restrict__ outProb)
{
    int w = threadIdx.x >> 6;
    int lane = threadIdx.x & 63;
    int b = blockIdx.x * 4 + w;
    const float* row = sgtg + (size_t)b * 512;
    float so = 0.f, to = 0.f;
#pragma unroll
    for (int u = 0; u < 4; ++u) {
        int c = lane + 64 * u;
        so = fmaf(row[c], W_so[c], so);
        to = fmaf(row[256 + c], W_to[c], to);
    }
#pragma unroll
    for (int off = 32; off; off >>= 1) {
        so += __shfl_down(so, off);
        to += __shfl_down(to, off);
    }
    so = __shfl(so, 0);
    to = __shfl(to, 0);
    float delta = sigm(so + b_so[0]);
    float thr   = sigm(to + b_to[0]);
    float cu = cum[b];
    float prob = cu + fminf(delta, 1.0f - cu);
    float hard = (prob > thr) ? 1.0f : 0.0f;
    if (lane == 0) {
        outDelta[b] = delta;
        outProb[b]  = prob;
        outCum[b]   = (1.0f - hard) * prob;
    }
    if (hard == 0.0f) {
#pragma unroll
        for (int u = 0; u < 8; ++u) {
            size_t idx = (size_t)b * 512 + lane + 64 * u;
            outH[idx] = h0[idx];
            outC[idx] = c0[idx];
        }
    }
}

extern "C" void kernel_launch(void* const* d_in, const int* in_sizes, int n_in,
                              void* d_out, int out_size, void* d_ws, size_t ws_size,
                              hipStream_t stream)
{
    const float* x    = (const float*)d_in[0];
    const float* h0   = (const float*)d_in[1];
    const float* c0   = (const float*)d_in[2];
    const float* cum  = (const float*)d_in[3];
    const float* W_ih = (const float*)d_in[4];
    const float* W_hh = (const float*)d_in[5];
    const float* b_ih = (const float*)d_in[6];
    const float* b_hh = (const float*)d_in[7];
    const float* W_sp = (const float*)d_in[8];
    const float* b_sp = (const float*)d_in[9];
    const float* W_sc = (const float*)d_in[10];
    const float* b_sc = (const float*)d_in[11];
    const float* W_so = (const float*)d_in[12];
    const float* b_so = (const float*)d_in[13];
    const float* W_tp = (const float*)d_in[14];
    const float* b_tp = (const float*)d_in[15];
    const float* W_to = (const float*)d_in[16];
    const float* b_to = (const float*)d_in[17];

    float* out      = (float*)d_out;
    float* outH     = out;
    float* outC     = out + (size_t)BB * HH;
    float* outCum   = out + (size_t)2 * BB * HH;
    float* outDelta = outCum + BB;
    float* outProb  = outDelta + BB;

    char* w = (char*)d_ws;
    ushort_t* A1h = (ushort_t*)(w);                       // 33,554,432 B
    ushort_t* A1l = (ushort_t*)(w + 33554432ull);         // 33,554,432 B
    ushort_t* A2h = (ushort_t*)(w + 67108864ull);         // 33,554,432 B
    ushort_t* A2l = (ushort_t*)(w + 100663296ull);        // 33,554,432 B
    ushort_t* B1h = (ushort_t*)(w + 134217728ull);        //  4,194,304 B
    ushort_t* B1l = (ushort_t*)(w + 138412032ull);        //  4,194,304 B
    ushort_t* B2h = (ushort_t*)(w + 142606336ull);        //  1,048,576 B
    ushort_t* B2l = (ushort_t*)(w + 143654912ull);        //  1,048,576 B
    float*    bgp = (float*)(w + 144703488ull);           //      8,192 B
    float*    bs2 = (float*)(w + 144711680ull);           //      2,048 B
    float*    sgtg = (float*)A1h;   // alias: A1 dead after k_gemm_gates

    k_prep_all<<<13568, 256, 0, stream>>>(x, h0, c0, W_ih, W_hh, b_ih, b_hh,
                                          W_sp, W_sc, W_tp, b_sp, b_sc, b_tp,
                                          A1h, A1l, A2h, A2l, B1h, B1l, B2h, B2l,
                                          bgp, bs2);
    k_gemm_gates<<<1024, 256, 0, stream>>>(A1h, A1l, B1h, B1l, bgp, c0,
                                           outH, outC, A2h, A2l);
    k_gemm_sgtg<<<512, 256, 0, stream>>>(A2h, A2l, B2h, B2l, bs2, sgtg);
    k_final<<<4096, 256, 0, stream>>>(sgtg, h0, c0, cum, W_so, b_so, W_to, b_to,
                                      outH, outC, outCum, outDelta, outProb);
}

// Round 8
// 343.021 us; speedup vs baseline: 1.1181x; 1.1181x over previous
//
#include <hip/hip_runtime.h>
#include <math.h>

#define BB 16384
#define HH 512

typedef short short8 __attribute__((ext_vector_type(8)));
typedef float f32x4 __attribute__((ext_vector_type(4)));
typedef unsigned short ushort_t;

__device__ __forceinline__ float sigm(float v){ return 1.0f/(1.0f+expf(-v)); }

__device__ __forceinline__ unsigned short f2bf(float f){
    unsigned int u = __float_as_uint(f);
    u = u + 0x7FFFu + ((u>>16)&1u);
    return (unsigned short)(u>>16);
}
__device__ __forceinline__ float bf2f(unsigned short h){
    return __uint_as_float(((unsigned int)h)<<16);
}
__device__ __forceinline__ void gll16(const void* g, void* l){
    __builtin_amdgcn_global_load_lds((const __attribute__((address_space(1))) void*)g,
                                     (__attribute__((address_space(3))) void*)l, 16, 0, 0);
}
__device__ __forceinline__ void split_store(float v, ushort_t* ph, ushort_t* pl, int j){
    unsigned short h = f2bf(v);
    unsigned short l = f2bf(v - bf2f(h));
    ph[j] = h; pl[j] = l;
}

// ---------------- merged prepass ----------------
// A1: [tm(64) 256-row][kt 32][c 4][r 256][8]  (8192 elems / (tm,kt))
// A2: [tm(128) 128-row][tk 32][c 4][r 128][8] (4096 elems)
// B1: [tn(16) 128-col][kt 32][c 4][col 128][8], gate-permuted: col -> (wcp=col>>6,
//     g=(col>>4)&3, h16=col&15), h = tn*32 + wcp*16 + h16, wrow = g*512+h
// B2: [tn(4) 128-col][tk 32][c 4][col 128][8]
__global__ void k_prep_all(
    const float* __restrict__ x, const float* __restrict__ h0, const float* __restrict__ c0,
    const float* __restrict__ W_ih, const float* __restrict__ W_hh,
    const float* __restrict__ b_ih, const float* __restrict__ b_hh,
    const float* __restrict__ W_sp, const float* __restrict__ W_sc, const float* __restrict__ W_tp,
    const float* __restrict__ b_sp, const float* __restrict__ b_sc, const float* __restrict__ b_tp,
    ushort_t* __restrict__ A1h, ushort_t* __restrict__ A1l,
    ushort_t* __restrict__ A2h, ushort_t* __restrict__ A2l,
    ushort_t* __restrict__ B1h, ushort_t* __restrict__ B1l,
    ushort_t* __restrict__ B2h, ushort_t* __restrict__ B2l,
    float* __restrict__ bgp, float* __restrict__ bs2)
{
    int bid = blockIdx.x;
    if (bid < 8192) {
        int u = bid*256 + threadIdx.x;
        int r  = u & 255;
        int c  = (u >> 8) & 3;
        int kt = (u >> 10) & 31;
        int tm = u >> 15;
        int row = tm*256 + r;
        int k0 = kt*32 + c*8;
        const float* src = (k0 < 512) ? (x + (size_t)row*512 + k0)
                                      : (h0 + (size_t)row*512 + (k0-512));
        float4 v0 = *(const float4*)(src);
        float4 v1 = *(const float4*)(src+4);
        float vv[8] = {v0.x,v0.y,v0.z,v0.w,v1.x,v1.y,v1.z,v1.w};
        size_t off = (size_t)u * 8;
#pragma unroll
        for (int j=0;j<8;++j) split_store(vv[j], A1h+off, A1l+off, j);
    } else if (bid < 12288) {
        int u = (bid-8192)*256 + threadIdx.x;
        int r  = u & 127;
        int c  = (u >> 7) & 3;
        int tk = (u >> 9) & 15;
        int tm = u >> 13;
        int row = tm*128 + r;
        int k0 = tk*32 + c*8;
        const float* src = c0 + (size_t)row*512 + k0;
        float4 v0 = *(const float4*)(src);
        float4 v1 = *(const float4*)(src+4);
        float vv[8] = {v0.x,v0.y,v0.z,v0.w,v1.x,v1.y,v1.z,v1.w};
        size_t off = ((size_t)tm*32 + tk)*4096 + (size_t)(c*128 + r)*8;
#pragma unroll
        for (int j=0;j<8;++j) split_store(vv[j], A2h+off, A2l+off, j);
    } else if (bid < 13312) {
        int u = (bid-12288)*256 + threadIdx.x;     // 262,144 over [tn16][kt32][c4][col128]
        int col = u & 127;
        int c  = (u >> 7) & 3;
        int kt = (u >> 9) & 31;
        int tn = u >> 14;
        int g = (col>>4)&3;
        int h = tn*32 + (col>>6)*16 + (col&15);
        int wrow = g*512 + h;
        int k0 = kt*32 + c*8;
        const float* src = (k0 < 512) ? (W_ih + (size_t)wrow*512 + k0)
                                      : (W_hh + (size_t)wrow*512 + (k0-512));
        float4 v0 = *(const float4*)(src);
        float4 v1 = *(const float4*)(src+4);
        float vv[8] = {v0.x,v0.y,v0.z,v0.w,v1.x,v1.y,v1.z,v1.w};
        size_t off = (size_t)u * 8;
#pragma unroll
        for (int j=0;j<8;++j) split_store(vv[j], B1h+off, B1l+off, j);
        if (kt == 0 && c == 0) bgp[tn*128 + col] = b_ih[wrow] + b_hh[wrow];
    } else {
        int u = (bid-13312)*256 + threadIdx.x;
        int r  = u & 127;
        int c  = (u >> 7) & 3;
        int tk = (u >> 9) & 31;
        int tn = u >> 14;
        int n = tn*128 + r;
        int k0 = tk*32 + c*8;
        float vv[8];
        if (n < 256) {
            const float* src = (k0 < 512) ? (W_sp + (size_t)n*512 + k0)
                                          : (W_sc + (size_t)n*512 + (k0-512));
            float4 v0 = *(const float4*)(src);
            float4 v1 = *(const float4*)(src+4);
            vv[0]=v0.x; vv[1]=v0.y; vv[2]=v0.z; vv[3]=v0.w;
            vv[4]=v1.x; vv[5]=v1.y; vv[6]=v1.z; vv[7]=v1.w;
        } else if (k0 < 512) {
            const float* src = W_tp + (size_t)(n-256)*512 + k0;
            float4 v0 = *(const float4*)(src);
            float4 v1 = *(const float4*)(src+4);
            vv[0]=v0.x; vv[1]=v0.y; vv[2]=v0.z; vv[3]=v0.w;
            vv[4]=v1.x; vv[5]=v1.y; vv[6]=v1.z; vv[7]=v1.w;
        } else {
#pragma unroll
            for (int j=0;j<8;++j) vv[j] = 0.0f;
        }
        size_t off = (size_t)u * 8;
#pragma unroll
        for (int j=0;j<8;++j) split_store(vv[j], B2h+off, B2l+off, j);
        if (tk == 0 && c == 0) bs2[n] = (n < 256) ? (b_sp[n] + b_sc[n]) : b_tp[n-256];
    }
}

// ---------- GEMM1: gates, 256x128 tile, 4 waves, depth-3 LDS, 2 blocks/CU ----------
// K-steps 0-31: Ah*Bh ; 32-63: Al*Bh ; 64-95: Ah*Bl
// Step K: stage tile K+2 -> buf BS, read frags K+1 from buf BR, MFMA on regs of K.
#define GSTEP(K, CA, CB, NA, NB, BR, BS, DO_READS, DO_STAGE, WAITASM)                \
  {                                                                                  \
    if (DO_STAGE) {                                                                  \
        const int uu = (K) + 2;                                                      \
        const ushort_t* As_ = ((uu >> 5) == 1) ? Al : Ah;                            \
        const ushort_t* Bs_ = ((uu >> 5) == 2) ? Bl : Bh;                            \
        const ushort_t* gA = As_ + ((size_t)tm*32 + (uu & 31))*8192;                 \
        const ushort_t* gB = Bs_ + ((size_t)tn*32 + (uu & 31))*4096;                 \
        ushort_t* dA = &lds[(BS)][0];                                                \
        ushort_t* dB = &lds[(BS)][8192];                                             \
        _Pragma("unroll") for (int q = 0; q < 4; ++q)                                \
            gll16(gA + (q*256 + tid)*8, dA + (q*256 + tid)*8);                       \
        _Pragma("unroll") for (int q = 0; q < 2; ++q)                                \
            gll16(gB + (q*256 + tid)*8, dB + (q*256 + tid)*8);                       \
    }                                                                                \
    if (DO_READS) {                                                                  \
        const ushort_t* bA = &lds[(BR)][0];                                          \
        const ushort_t* bB = &lds[(BR)][8192];                                       \
        _Pragma("unroll") for (int f = 0; f < 8; ++f)                                \
            NA[f] = *(const short8*)&bA[aoff[f]];                                    \
        _Pragma("unroll") for (int f = 0; f < 4; ++f)                                \
            NB[f] = *(const short8*)&bB[boff[f]];                                    \
    }                                                                                \
    __builtin_amdgcn_sched_barrier(0);                                               \
    __builtin_amdgcn_s_setprio(1);                                                   \
    _Pragma("unroll") for (int fm = 0; fm < 8; ++fm)                                 \
        _Pragma("unroll") for (int fn = 0; fn < 4; ++fn)                             \
            acc[fm][fn] = __builtin_amdgcn_mfma_f32_16x16x32_bf16(CA[fm], CB[fn], acc[fm][fn], 0,0,0); \
    __builtin_amdgcn_s_setprio(0);                                                   \
    asm volatile("s_waitcnt lgkmcnt(0)" ::: "memory");                               \
    __builtin_amdgcn_sched_barrier(0);                                               \
    WAITASM;                                                                         \
    __builtin_amdgcn_sched_barrier(0);                                               \
    asm volatile("s_barrier" ::: "memory");                                          \
  }
#define VM0 asm volatile("s_waitcnt vmcnt(0)" ::: "memory")

__global__ __launch_bounds__(256, 2) void k_gemm_gates(
    const ushort_t* __restrict__ Ah, const ushort_t* __restrict__ Al,
    const ushort_t* __restrict__ Bh, const ushort_t* __restrict__ Bl,
    const float* __restrict__ bgp, const float* __restrict__ c0,
    float* __restrict__ outH, float* __restrict__ outC,
    ushort_t* __restrict__ A2h, ushort_t* __restrict__ A2l)
{
    __shared__ __align__(16) ushort_t lds[3][12288];   // 72 KiB -> 2 blocks/CU
    const int tid  = threadIdx.x;
    const int lane = tid & 63;
    const int wid  = tid >> 6;
    const int wr   = wid >> 1;        // 0..1 -> rows wr*128
    const int wc   = wid & 1;         // 0..1 -> cols wc*64
    const int l15  = lane & 15;
    const int lq   = lane >> 4;
    const int bid  = (int)blockIdx.x;
    const int v    = (bid & 7)*128 + (bid >> 3);   // XCD swizzle (1024 blocks)
    const int tm   = v >> 4;          // 0..63  (256-row tiles)
    const int tn   = v & 15;          // 0..15  (128-gatecol tiles)

    f32x4 acc[8][4];
#pragma unroll
    for (int fn = 0; fn < 4; ++fn) {
        float bv = bgp[tn*128 + wc*64 + fn*16 + l15];
#pragma unroll
        for (int fm = 0; fm < 8; ++fm) {
            acc[fm][fn][0]=bv; acc[fm][fn][1]=bv; acc[fm][fn][2]=bv; acc[fm][fn][3]=bv;
        }
    }

    int aoff[8], boff[4];
#pragma unroll
    for (int f = 0; f < 8; ++f) aoff[f] = (lq*256 + wr*128 + f*16 + l15) * 8;
#pragma unroll
    for (int f = 0; f < 4; ++f) boff[f] = (lq*128 + wc*64 + f*16 + l15) * 8;

    short8 a0[8], b0[4], a1[8], b1[4];

    // prologue: stage tiles 0,1 into buf 0,1; drain; read tile-0 frags
#pragma unroll
    for (int u0 = 0; u0 < 2; ++u0) {
        const ushort_t* gA = Ah + ((size_t)tm*32 + u0)*8192;
        const ushort_t* gB = Bh + ((size_t)tn*32 + u0)*4096;
#pragma unroll
        for (int q = 0; q < 4; ++q)
            gll16(gA + (q*256 + tid)*8, &lds[u0][(q*256 + tid)*8]);
#pragma unroll
        for (int q = 0; q < 2; ++q)
            gll16(gB + (q*256 + tid)*8, &lds[u0][8192 + (q*256 + tid)*8]);
    }
    asm volatile("s_waitcnt vmcnt(0)" ::: "memory");
    asm volatile("s_barrier" ::: "memory");
#pragma unroll
    for (int f = 0; f < 8; ++f) a0[f] = *(const short8*)&lds[0][aoff[f]];
#pragma unroll
    for (int f = 0; f < 4; ++f) b0[f] = *(const short8*)&lds[0][8192 + boff[f]];
    asm volatile("s_waitcnt lgkmcnt(0)" ::: "memory");
    __builtin_amdgcn_sched_barrier(0);

    for (int t = 0; t < 90; t += 6) {
        GSTEP(t+0, a0,b0, a1,b1, 1,2, 1,1, VM0);
        GSTEP(t+1, a1,b1, a0,b0, 2,0, 1,1, VM0);
        GSTEP(t+2, a0,b0, a1,b1, 0,1, 1,1, VM0);
        GSTEP(t+3, a1,b1, a0,b0, 1,2, 1,1, VM0);
        GSTEP(t+4, a0,b0, a1,b1, 2,0, 1,1, VM0);
        GSTEP(t+5, a1,b1, a0,b0, 0,1, 1,1, VM0);
    }
    GSTEP(90, a0,b0, a1,b1, 1,2, 1,1, VM0);
    GSTEP(91, a1,b1, a0,b0, 2,0, 1,1, VM0);
    GSTEP(92, a0,b0, a1,b1, 0,1, 1,1, VM0);
    GSTEP(93, a1,b1, a0,b0, 1,2, 1,1, VM0);
    GSTEP(94, a0,b0, a1,b1, 2,0, 1,0, VM0);
    GSTEP(95, a1,b1, a0,b0, 0,0, 0,0, ((void)0));

    // epilogue: lane holds 4 gates (fn) for rows lq*4+r, col h
    const int h = tn*32 + wc*16 + l15;
#pragma unroll
    for (int fm = 0; fm < 8; ++fm) {
        int row0 = tm*256 + wr*128 + fm*16 + lq*4;
#pragma unroll
        for (int r = 0; r < 4; ++r) {
            int row = row0 + r;
            size_t idx = (size_t)row*512 + h;
            float ig = sigm(acc[fm][0][r]);
            float fg = sigm(acc[fm][1][r]);
            float gg = tanhf(acc[fm][2][r]);
            float og = sigm(acc[fm][3][r]);
            float c1 = fg*c0[idx] + ig*gg;
            float h1 = og*tanhf(c1);
            outC[idx] = c1;
            outH[idx] = h1;
            unsigned short ch = f2bf(c1);
            unsigned short cl = f2bf(c1 - bf2f(ch));
            size_t a2 = ((size_t)(row>>7)*32 + 16 + (h>>5))*4096
                      + (size_t)((((h>>3)&3))*128 + (row&127))*8 + (h&7);
            A2h[a2] = ch;
            A2l[a2] = cl;
        }
    }
}

// ---------- GEMM2: sg|tg, 128x128, K''=3072, r5 ping-pong pipeline (verbatim) ----------
#define SSTEP(T, CA, CB, NA, NB, DO_READS, DO_STAGE, VMASM)                          \
  {                                                                                  \
    if (DO_READS) {                                                                  \
        const ushort_t* bufA1 = &lds2[((T)+1) & 3][0];                               \
        const ushort_t* bufB1 = &lds2[((T)+1) & 3][4096];                            \
        _Pragma("unroll") for (int f = 0; f < 4; ++f)                                \
            NA[f] = *(const short8*)&bufA1[aoff[f]];                                 \
        _Pragma("unroll") for (int f = 0; f < 4; ++f)                                \
            NB[f] = *(const short8*)&bufB1[boff[f]];                                 \
    }                                                                                \
    if (DO_STAGE) {                                                                  \
        const int uu = (T) + 3;                                                      \
        const ushort_t* As_ = ((uu >> 5) == 1) ? Al : Ah;                            \
        const ushort_t* Bs_ = ((uu >> 5) == 2) ? Bl : Bh;                            \
        size_t ga = ((size_t)tm*32 + (uu & 31))*4096 + (size_t)tid*8;                \
        size_t gb = ((size_t)tn*32 + (uu & 31))*4096 + (size_t)tid*8;                \
        ushort_t* dA = &lds2[uu & 3][0];                                             \
        ushort_t* dB = &lds2[uu & 3][4096];                                          \
        gll16(As_ + ga,        dA + tid*8);                                          \
        gll16(As_ + ga + 2048, dA + 2048 + tid*8);                                   \
        gll16(Bs_ + gb,        dB + tid*8);                                          \
        gll16(Bs_ + gb + 2048, dB + 2048 + tid*8);                                   \
    }                                                                                \
    __builtin_amdgcn_sched_barrier(0);                                               \
    __builtin_amdgcn_s_setprio(1);                                                   \
    _Pragma("unroll") for (int fm = 0; fm < 4; ++fm)                                 \
        _Pragma("unroll") for (int fn = 0; fn < 4; ++fn)                             \
            acc[fm][fn] = __builtin_amdgcn_mfma_f32_16x16x32_bf16(CA[fm], CB[fn], acc[fm][fn], 0,0,0); \
    __builtin_amdgcn_s_setprio(0);                                                   \
    asm volatile("s_waitcnt lgkmcnt(0)" ::: "memory");                               \
    __builtin_amdgcn_sched_barrier(0);                                               \
    VMASM;                                                                           \
    asm volatile("s_barrier" ::: "memory");                                          \
  }

__global__ __launch_bounds__(256, 2) void k_gemm_sgtg(
    const ushort_t* __restrict__ Ah, const ushort_t* __restrict__ Al,
    const ushort_t* __restrict__ Bh, const ushort_t* __restrict__ Bl,
    const float* __restrict__ bs2,
    float* __restrict__ sgtg)
{
    __shared__ __align__(16) ushort_t lds2[4][8192];   // 64 KiB -> 2 blocks/CU
    const int tid  = threadIdx.x;
    const int lane = tid & 63;
    const int wid  = tid >> 6;
    const int wr   = wid >> 1;
    const int wc   = wid & 1;
    const int l15  = lane & 15;
    const int lq   = lane >> 4;
    const int bid  = (int)blockIdx.x;
    const int v    = (bid & 7)*64 + (bid >> 3);
    const int tm   = v >> 2;          // 0..127
    const int tn   = v & 3;           // 0..3

    f32x4 acc[4][4];
#pragma unroll
    for (int fn = 0; fn < 4; ++fn) {
        float bv = bs2[tn*128 + wc*64 + fn*16 + l15];
#pragma unroll
        for (int fm = 0; fm < 4; ++fm) {
            acc[fm][fn][0]=bv; acc[fm][fn][1]=bv; acc[fm][fn][2]=bv; acc[fm][fn][3]=bv;
        }
    }

    int aoff[4], boff[4];
#pragma unroll
    for (int f = 0; f < 4; ++f) {
        aoff[f] = (lq*128 + wr*64 + f*16 + l15) * 8;
        boff[f] = (lq*128 + wc*64 + f*16 + l15) * 8;
    }

    short8 a0[4], b0[4], a1[4], b1[4];

#pragma unroll
    for (int u0 = 0; u0 < 3; ++u0) {
        size_t ga = ((size_t)tm*32 + u0)*4096 + (size_t)tid*8;
        size_t gb = ((size_t)tn*32 + u0)*4096 + (size_t)tid*8;
        gll16(Ah + ga,        &lds2[u0][0]    + tid*8);
        gll16(Ah + ga + 2048, &lds2[u0][2048] + tid*8);
        gll16(Bh + gb,        &lds2[u0][4096] + tid*8);
        gll16(Bh + gb + 2048, &lds2[u0][6144] + tid*8);
    }
    asm volatile("s_waitcnt vmcnt(4)" ::: "memory");
    asm volatile("s_barrier" ::: "memory");
#pragma unroll
    for (int f = 0; f < 4; ++f) a0[f] = *(const short8*)&lds2[0][aoff[f]];
#pragma unroll
    for (int f = 0; f < 4; ++f) b0[f] = *(const short8*)&lds2[0][4096 + boff[f]];
    asm volatile("s_waitcnt lgkmcnt(0)" ::: "memory");
    __builtin_amdgcn_sched_barrier(0);

    for (int t = 0; t < 92; t += 2) {
        SSTEP(t,   a0, b0, a1, b1, 1, 1, asm volatile("s_waitcnt vmcnt(4)" ::: "memory"));
        SSTEP(t+1, a1, b1, a0, b0, 1, 1, asm volatile("s_waitcnt vmcnt(4)" ::: "memory"));
    }
    SSTEP(92, a0, b0, a1, b1, 1, 1, asm volatile("s_waitcnt vmcnt(4)" ::: "memory"));
    SSTEP(93, a1, b1, a0, b0, 1, 0, asm volatile("s_waitcnt vmcnt(0)" ::: "memory"));
    SSTEP(94, a0, b0, a1, b1, 1, 0, ((void)0));
    SSTEP(95, a1, b1, a0, b0, 0, 0, ((void)0));

#pragma unroll
    for (int fm = 0; fm < 4; ++fm) {
        int row0 = tm*128 + wr*64 + fm*16 + lq*4;
#pragma unroll
        for (int fn = 0; fn < 4; ++fn) {
            int n = tn*128 + wc*64 + fn*16 + l15;
#pragma unroll
            for (int r = 0; r < 4; ++r) {
                int row = row0 + r;
                float vv = acc[fm][fn][r];
                vv = vv > 0.f ? vv : 0.01f*vv;
                sgtg[(size_t)row*512 + n] = vv;
            }
        }
    }
}

// ---------- final: row dots, threshold decision, gated writeback ----------
__global__ __launch_bounds__(256) void k_final(
    const float* __restrict__ sgtg,
    const float* __restrict__ h0, const float* __restrict__ c0,
    const float* __restrict__ cum,
    const float* __restrict__ W_so, const float* __restrict__ b_so,
    const float* __restrict__ W_to, const float* __restrict__ b_to,
    float* __restrict__ outH, float* __restrict__ outC,
    float* __restrict__ outCum, float* __restrict__ outDelta, float* __restrict__ outProb)
{
    int w = threadIdx.x >> 6;
    int lane = threadIdx.x & 63;
    int b = blockIdx.x * 4 + w;
    const float* row = sgtg + (size_t)b * 512;
    float so = 0.f, to = 0.f;
#pragma unroll
    for (int u = 0; u < 4; ++u) {
        int c = lane + 64 * u;
        so = fmaf(row[c], W_so[c], so);
        to = fmaf(row[256 + c], W_to[c], to);
    }
#pragma unroll
    for (int off = 32; off; off >>= 1) {
        so += __shfl_down(so, off);
        to += __shfl_down(to, off);
    }
    so = __shfl(so, 0);
    to = __shfl(to, 0);
    float delta = sigm(so + b_so[0]);
    float thr   = sigm(to + b_to[0]);
    float cu = cum[b];
    float prob = cu + fminf(delta, 1.0f - cu);
    float hard = (prob > thr) ? 1.0f : 0.0f;
    if (lane == 0) {
        outDelta[b] = delta;
        outProb[b]  = prob;
        outCum[b]   = (1.0f - hard) * prob;
    }
    if (hard == 0.0f) {
#pragma unroll
        for (int u = 0; u < 8; ++u) {
            size_t idx = (size_t)b * 512 + lane + 64 * u;
            outH[idx] = h0[idx];
            outC[idx] = c0[idx];
        }
    }
}

extern "C" void kernel_launch(void* const* d_in, const int* in_sizes, int n_in,
                              void* d_out, int out_size, void* d_ws, size_t ws_size,
                              hipStream_t stream)
{
    const float* x    = (const float*)d_in[0];
    const float* h0   = (const float*)d_in[1];
    const float* c0   = (const float*)d_in[2];
    const float* cum  = (const float*)d_in[3];
    const float* W_ih = (const float*)d_in[4];
    const float* W_hh = (const float*)d_in[5];
    const float* b_ih = (const float*)d_in[6];
    const float* b_hh = (const float*)d_in[7];
    const float* W_sp = (const float*)d_in[8];
    const float* b_sp = (const float*)d_in[9];
    const float* W_sc = (const float*)d_in[10];
    const float* b_sc = (const float*)d_in[11];
    const float* W_so = (const float*)d_in[12];
    const float* b_so = (const float*)d_in[13];
    const float* W_tp = (const float*)d_in[14];
    const float* b_tp = (const float*)d_in[15];
    const float* W_to = (const float*)d_in[16];
    const float* b_to = (const float*)d_in[17];

    float* out      = (float*)d_out;
    float* outH     = out;
    float* outC     = out + (size_t)BB * HH;
    float* outCum   = out + (size_t)2 * BB * HH;
    float* outDelta = outCum + BB;
    float* outProb  = outDelta + BB;

    char* w = (char*)d_ws;
    ushort_t* A1h = (ushort_t*)(w);                       // 33,554,432 B
    ushort_t* A1l = (ushort_t*)(w + 33554432ull);         // 33,554,432 B
    ushort_t* A2h = (ushort_t*)(w + 67108864ull);         // 33,554,432 B
    ushort_t* A2l = (ushort_t*)(w + 100663296ull);        // 33,554,432 B
    ushort_t* B1h = (ushort_t*)(w + 134217728ull);        //  4,194,304 B
    ushort_t* B1l = (ushort_t*)(w + 138412032ull);        //  4,194,304 B
    ushort_t* B2h = (ushort_t*)(w + 142606336ull);        //  1,048,576 B
    ushort_t* B2l = (ushort_t*)(w + 143654912ull);        //  1,048,576 B
    float*    bgp = (float*)(w + 144703488ull);           //      8,192 B
    float*    bs2 = (float*)(w + 144711680ull);           //      2,048 B
    float*    sgtg = (float*)A1h;   // alias: A1 dead after k_gemm_gates

    k_prep_all<<<13568, 256, 0, stream>>>(x, h0, c0, W_ih, W_hh, b_ih, b_hh,
                                          W_sp, W_sc, W_tp, b_sp, b_sc, b_tp,
                                          A1h, A1l, A2h, A2l, B1h, B1l, B2h, B2l,
                                          bgp, bs2);
    k_gemm_gates<<<1024, 256, 0, stream>>>(A1h, A1l, B1h, B1l, bgp, c0,
                                           outH, outC, A2h, A2l);
    k_gemm_sgtg<<<512, 256, 0, stream>>>(A2h, A2l, B2h, B2l, bs2, sgtg);
    k_final<<<4096, 256, 0, stream>>>(sgtg, h0, c0, cum, W_so, b_so, W_to, b_to,
                                      outH, outC, outCum, outDelta, outProb);
}

// Round 9
// 339.771 us; speedup vs baseline: 1.1288x; 1.0096x over previous
//
#include <hip/hip_runtime.h>
#include <math.h>

#define BB 16384
#define HH 512

typedef short short8 __attribute__((ext_vector_type(8)));
typedef float f32x4 __attribute__((ext_vector_type(4)));
typedef unsigned short ushort_t;

__device__ __forceinline__ float sigm(float v){ return 1.0f/(1.0f+expf(-v)); }

__device__ __forceinline__ unsigned short f2bf(float f){
    unsigned int u = __float_as_uint(f);
    u = u + 0x7FFFu + ((u>>16)&1u);
    return (unsigned short)(u>>16);
}
__device__ __forceinline__ float bf2f(unsigned short h){
    return __uint_as_float(((unsigned int)h)<<16);
}
__device__ __forceinline__ void gll16(const void* g, void* l){
    __builtin_amdgcn_global_load_lds((const __attribute__((address_space(1))) void*)g,
                                     (__attribute__((address_space(3))) void*)l, 16, 0, 0);
}
__device__ __forceinline__ void split_store(float v, ushort_t* ph, ushort_t* pl, int j){
    unsigned short h = f2bf(v);
    unsigned short l = f2bf(v - bf2f(h));
    ph[j] = h; pl[j] = l;
}

// ---------------- merged prepass ----------------
// A1: [tm 64][kt 16 (K64)][half 2][c 8][rr 128][8]; rr = wr(1)|q2(2)|l15(4);
//     row = tm*256 + wr*128 + (half*4+q2)*16 + l15 ; k = kt*64 + c*8 + j
// B1: [tn 8][kt 16][half 2][c 8][cc 128][8]; cc = wcg(2)|fn1(1)|h16(4);
//     gate g = half*2+fn1 ; h = tn*64 + wcg*16 + h16 ; wrow = g*512+h
// A2: [tm 128][tk 32][c 4][r 128][8] (lo half from c0) ; B2: as before
__global__ void k_prep_all(
    const float* __restrict__ x, const float* __restrict__ h0, const float* __restrict__ c0,
    const float* __restrict__ W_ih, const float* __restrict__ W_hh,
    const float* __restrict__ b_ih, const float* __restrict__ b_hh,
    const float* __restrict__ W_sp, const float* __restrict__ W_sc, const float* __restrict__ W_tp,
    const float* __restrict__ b_sp, const float* __restrict__ b_sc, const float* __restrict__ b_tp,
    ushort_t* __restrict__ A1h, ushort_t* __restrict__ A1l,
    ushort_t* __restrict__ A2h, ushort_t* __restrict__ A2l,
    ushort_t* __restrict__ B1h, ushort_t* __restrict__ B1l,
    ushort_t* __restrict__ B2h, ushort_t* __restrict__ B2l,
    float* __restrict__ bgp, float* __restrict__ bs2)
{
    int bid = blockIdx.x;
    if (bid < 8192) {
        int u = bid*256 + threadIdx.x;
        int rr   = u & 127;
        int c    = (u >> 7) & 7;
        int half = (u >> 10) & 1;
        int kt   = (u >> 11) & 15;
        int tm   = u >> 15;
        int wr = rr >> 6, q2 = (rr >> 4) & 3, l15 = rr & 15;
        int row = tm*256 + wr*128 + (half*4 + q2)*16 + l15;
        int k0  = kt*64 + c*8;
        const float* src = (k0 < 512) ? (x + (size_t)row*512 + k0)
                                      : (h0 + (size_t)row*512 + (k0-512));
        float4 v0 = *(const float4*)(src);
        float4 v1 = *(const float4*)(src+4);
        float vv[8] = {v0.x,v0.y,v0.z,v0.w,v1.x,v1.y,v1.z,v1.w};
        size_t off = (size_t)u * 8;
#pragma unroll
        for (int j=0;j<8;++j) split_store(vv[j], A1h+off, A1l+off, j);
    } else if (bid < 12288) {
        int u = (bid-8192)*256 + threadIdx.x;
        int r  = u & 127;
        int c  = (u >> 7) & 3;
        int tk = (u >> 9) & 15;
        int tm = u >> 13;
        int row = tm*128 + r;
        int k0 = tk*32 + c*8;
        const float* src = c0 + (size_t)row*512 + k0;
        float4 v0 = *(const float4*)(src);
        float4 v1 = *(const float4*)(src+4);
        float vv[8] = {v0.x,v0.y,v0.z,v0.w,v1.x,v1.y,v1.z,v1.w};
        size_t off = ((size_t)tm*32 + tk)*4096 + (size_t)(c*128 + r)*8;
#pragma unroll
        for (int j=0;j<8;++j) split_store(vv[j], A2h+off, A2l+off, j);
    } else if (bid < 13312) {
        int u = (bid-12288)*256 + threadIdx.x;
        int cc   = u & 127;
        int c    = (u >> 7) & 7;
        int half = (u >> 10) & 1;
        int kt   = (u >> 11) & 15;
        int tn   = u >> 15;
        int wcg = cc >> 5, fn1 = (cc >> 4) & 1, h16 = cc & 15;
        int g = half*2 + fn1;
        int h = tn*64 + wcg*16 + h16;
        int wrow = g*512 + h;
        int k0 = kt*64 + c*8;
        const float* src = (k0 < 512) ? (W_ih + (size_t)wrow*512 + k0)
                                      : (W_hh + (size_t)wrow*512 + (k0-512));
        float4 v0 = *(const float4*)(src);
        float4 v1 = *(const float4*)(src+4);
        float vv[8] = {v0.x,v0.y,v0.z,v0.w,v1.x,v1.y,v1.z,v1.w};
        size_t off = (size_t)u * 8;
#pragma unroll
        for (int j=0;j<8;++j) split_store(vv[j], B1h+off, B1l+off, j);
        if (kt == 0 && c == 0) bgp[tn*256 + g*64 + wcg*16 + h16] = b_ih[wrow] + b_hh[wrow];
    } else {
        int u = (bid-13312)*256 + threadIdx.x;
        int r  = u & 127;
        int c  = (u >> 7) & 3;
        int tk = (u >> 9) & 31;
        int tn = u >> 14;
        int n = tn*128 + r;
        int k0 = tk*32 + c*8;
        float vv[8];
        if (n < 256) {
            const float* src = (k0 < 512) ? (W_sp + (size_t)n*512 + k0)
                                          : (W_sc + (size_t)n*512 + (k0-512));
            float4 v0 = *(const float4*)(src);
            float4 v1 = *(const float4*)(src+4);
            vv[0]=v0.x; vv[1]=v0.y; vv[2]=v0.z; vv[3]=v0.w;
            vv[4]=v1.x; vv[5]=v1.y; vv[6]=v1.z; vv[7]=v1.w;
        } else if (k0 < 512) {
            const float* src = W_tp + (size_t)(n-256)*512 + k0;
            float4 v0 = *(const float4*)(src);
            float4 v1 = *(const float4*)(src+4);
            vv[0]=v0.x; vv[1]=v0.y; vv[2]=v0.z; vv[3]=v0.w;
            vv[4]=v1.x; vv[5]=v1.y; vv[6]=v1.z; vv[7]=v1.w;
        } else {
#pragma unroll
            for (int j=0;j<8;++j) vv[j] = 0.0f;
        }
        size_t off = (size_t)u * 8;
#pragma unroll
        for (int j=0;j<8;++j) split_store(vv[j], B2h+off, B2l+off, j);
        if (tk == 0 && c == 0) bs2[n] = (n < 256) ? (b_sp[n] + b_sc[n]) : b_tp[n-256];
    }
}

// ---------- GEMM1: gates, 256x256, BK=64, 8 waves, m201-style 4-phase K-tile ----------
#define QUAD(AF, BF, R0, C0)                                                         \
    _Pragma("unroll") for (int i2 = 0; i2 < 4; ++i2)                                 \
    _Pragma("unroll") for (int j2 = 0; j2 < 2; ++j2) {                               \
        acc[(R0)+i2][(C0)+j2] = __builtin_amdgcn_mfma_f32_16x16x32_bf16(             \
            AF[i2][0], BF[j2][0], acc[(R0)+i2][(C0)+j2], 0,0,0);                     \
        acc[(R0)+i2][(C0)+j2] = __builtin_amdgcn_mfma_f32_16x16x32_bf16(             \
            AF[i2][1], BF[j2][1], acc[(R0)+i2][(C0)+j2], 0,0,0);                     \
    }

#define STAGEH(SRC, GBASE, LDST)                                                     \
    gll16((SRC) + (GBASE) + (size_t)tid*8, (LDST) + tid*8);                          \
    gll16((SRC) + (GBASE) + 4096 + (size_t)tid*8, (LDST) + 4096 + tid*8);

#define PH_SYNC                                                                      \
    asm volatile("s_barrier" ::: "memory");                                          \
    asm volatile("s_waitcnt lgkmcnt(0)" ::: "memory");                               \
    __builtin_amdgcn_sched_barrier(0);

__global__ __launch_bounds__(512, 2) void k_gemm_gates(
    const ushort_t* __restrict__ Ah, const ushort_t* __restrict__ Al,
    const ushort_t* __restrict__ Bh, const ushort_t* __restrict__ Bl,
    const float* __restrict__ bgp, const float* __restrict__ c0,
    float* __restrict__ outH, float* __restrict__ outC,
    ushort_t* __restrict__ A2h, ushort_t* __restrict__ A2l)
{
    __shared__ __align__(16) ushort_t lds[2][32768];   // 128 KiB: [buf][A 16K | B 16K elems]
    const int tid  = threadIdx.x;
    const int lane = tid & 63;
    const int wid  = tid >> 6;
    const int wr   = wid >> 2;        // 0..1 -> rows wr*128
    const int wc   = wid & 3;         // 0..3 -> cols wc*64
    const int l15  = lane & 15;
    const int lq   = lane >> 4;
    const int bid  = (int)blockIdx.x;
    const int v    = (bid & 7)*64 + (bid >> 3);   // XCD swizzle (512 blocks)
    const int tm   = v >> 3;          // 0..63
    const int tn   = v & 7;           // 0..7

    f32x4 acc[8][4];
#pragma unroll
    for (int fn = 0; fn < 4; ++fn) {
        float bv = bgp[tn*256 + fn*64 + wc*16 + l15];
#pragma unroll
        for (int fm = 0; fm < 8; ++fm) {
            acc[fm][fn][0]=bv; acc[fm][fn][1]=bv; acc[fm][fn][2]=bv; acc[fm][fn][3]=bv;
        }
    }

    // ds_read offsets (elems): A frag (fm,kk), B frag (fn,kk)
    int aro[8][2], bro[4][2];
#pragma unroll
    for (int fm = 0; fm < 8; ++fm)
#pragma unroll
        for (int kk = 0; kk < 2; ++kk)
            aro[fm][kk] = (fm>>2)*8192 + (kk*4+lq)*1024 + (wr*64 + (fm&3)*16 + l15)*8;
#pragma unroll
    for (int fn = 0; fn < 4; ++fn)
#pragma unroll
        for (int kk = 0; kk < 2; ++kk)
            bro[fn][kk] = 16384 + (fn>>1)*8192 + (kk*4+lq)*1024 + (wc*32 + (fn&1)*16 + l15)*8;

    short8 a0[4][2], a1[4][2], b0[2][2], b1[2][2];

    // prologue: stage tile0 (A-h0,B-h0,A-h1,B-h1) + A-h0[1]; vmcnt(2); barrier
    {
        STAGEH(Ah, (size_t)((tm*16 + 0)*2 + 0)*8192, &lds[0][0]);
        STAGEH(Bh, (size_t)((tn*16 + 0)*2 + 0)*8192, &lds[0][16384]);
        STAGEH(Ah, (size_t)((tm*16 + 0)*2 + 1)*8192, &lds[0][8192]);
        STAGEH(Bh, (size_t)((tn*16 + 0)*2 + 1)*8192, &lds[0][24576]);
        STAGEH(Ah, (size_t)((tm*16 + 1)*2 + 0)*8192, &lds[1][0]);
    }
    asm volatile("s_waitcnt vmcnt(2)" ::: "memory");
    asm volatile("s_barrier" ::: "memory");

    for (int t = 0; t < 48; ++t) {
        const int u1 = t + 1, u2 = t + 2;
        const ushort_t* sA1 = ((u1 >> 4) == 1) ? Al : Ah;
        const ushort_t* sB1 = ((u1 >> 4) == 2) ? Bl : Bh;
        const ushort_t* sA2 = ((u2 >> 4) == 1) ? Al : Ah;
        const int ki1 = u1 & 15, ki2 = u2 & 15;
        const int st1 = (t <= 46), st4 = (t <= 45);
        ushort_t* bufc = &lds[t & 1][0];
        ushort_t* bufn = &lds[(t+1) & 1][0];

        // ---- PH1: read A0 (8) + B0 (4); stage B-h0[t+1]; MFMA A0xB0 ----
#pragma unroll
        for (int i2 = 0; i2 < 4; ++i2) {
            a0[i2][0] = *(const short8*)&bufc[aro[i2][0]];
            a0[i2][1] = *(const short8*)&bufc[aro[i2][1]];
        }
#pragma unroll
        for (int j2 = 0; j2 < 2; ++j2) {
            b0[j2][0] = *(const short8*)&bufc[bro[j2][0]];
            b0[j2][1] = *(const short8*)&bufc[bro[j2][1]];
        }
        if (st1) { STAGEH(sB1, (size_t)((tn*16 + ki1)*2 + 0)*8192, bufn + 16384); }
        PH_SYNC;
        __builtin_amdgcn_s_setprio(1);
        QUAD(a0, b0, 0, 0);
        __builtin_amdgcn_s_setprio(0);
        asm volatile("s_barrier" ::: "memory");

        // ---- PH2: read A1 (8); stage A-h1[t+1]; MFMA A1xB0 ----
#pragma unroll
        for (int i2 = 0; i2 < 4; ++i2) {
            a1[i2][0] = *(const short8*)&bufc[aro[4+i2][0]];
            a1[i2][1] = *(const short8*)&bufc[aro[4+i2][1]];
        }
        if (st1) { STAGEH(sA1, (size_t)((tm*16 + ki1)*2 + 1)*8192, bufn + 8192); }
        PH_SYNC;
        __builtin_amdgcn_s_setprio(1);
        QUAD(a1, b0, 4, 0);
        __builtin_amdgcn_s_setprio(0);
        asm volatile("s_barrier" ::: "memory");

        // ---- PH3: read B1 (4); stage B-h1[t+1]; MFMA A1xB1 ----
#pragma unroll
        for (int j2 = 0; j2 < 2; ++j2) {
            b1[j2][0] = *(const short8*)&bufc[bro[2+j2][0]];
            b1[j2][1] = *(const short8*)&bufc[bro[2+j2][1]];
        }
        if (st1) { STAGEH(sB1, (size_t)((tn*16 + ki1)*2 + 1)*8192, bufn + 24576); }
        PH_SYNC;
        __builtin_amdgcn_s_setprio(1);
        QUAD(a1, b1, 4, 2);
        __builtin_amdgcn_s_setprio(0);
        asm volatile("s_barrier" ::: "memory");

        // ---- PH4: stage A-h0[t+2] into CURRENT buf; counted vmcnt; MFMA A0xB1 ----
        if (st4) { STAGEH(sA2, (size_t)((tm*16 + ki2)*2 + 0)*8192, bufc + 0); }
        if (t >= 46) { asm volatile("s_waitcnt vmcnt(0)" ::: "memory"); }
        else         { asm volatile("s_waitcnt vmcnt(2)" ::: "memory"); }
        __builtin_amdgcn_sched_barrier(0);
        asm volatile("s_barrier" ::: "memory");
        __builtin_amdgcn_s_setprio(1);
        QUAD(a0, b1, 0, 2);
        __builtin_amdgcn_s_setprio(0);
        asm volatile("s_barrier" ::: "memory");
    }

    // epilogue: acc[fm][gate]; row = tm*256 + wr*128 + fm*16 + lq*4 + r ; h = tn*64 + wc*16 + l15
    const int h = tn*64 + wc*16 + l15;
#pragma unroll
    for (int fm = 0; fm < 8; ++fm) {
        int row0 = tm*256 + wr*128 + fm*16 + lq*4;
#pragma unroll
        for (int r = 0; r < 4; ++r) {
            int row = row0 + r;
            size_t idx = (size_t)row*512 + h;
            float ig = sigm(acc[fm][0][r]);
            float fg = sigm(acc[fm][1][r]);
            float gg = tanhf(acc[fm][2][r]);
            float og = sigm(acc[fm][3][r]);
            float c1 = fg*c0[idx] + ig*gg;
            float h1 = og*tanhf(c1);
            outC[idx] = c1;
            outH[idx] = h1;
            unsigned short ch = f2bf(c1);
            unsigned short cl = f2bf(c1 - bf2f(ch));
            size_t a2 = ((size_t)(row>>7)*32 + 16 + (h>>5))*4096
                      + (size_t)((((h>>3)&3))*128 + (row&127))*8 + (h&7);
            A2h[a2] = ch;
            A2l[a2] = cl;
        }
    }
}

// ---------- GEMM2: sg|tg, 128x128, K''=3072, r5 ping-pong pipeline (unchanged) ----------
#define SSTEP(T, CA, CB, NA, NB, DO_READS, DO_STAGE, VMASM)                          \
  {                                                                                  \
    if (DO_READS) {                                                                  \
        const ushort_t* bufA1 = &lds2[((T)+1) & 3][0];                               \
        const ushort_t* bufB1 = &lds2[((T)+1) & 3][4096];                            \
        _Pragma("unroll") for (int f = 0; f < 4; ++f)                                \
            NA[f] = *(const short8*)&bufA1[aoff[f]];                                 \
        _Pragma("unroll") for (int f = 0; f < 4; ++f)                                \
            NB[f] = *(const short8*)&bufB1[boff[f]];                                 \
    }                                                                                \
    if (DO_STAGE) {                                                                  \
        const int uu = (T) + 3;                                                      \
        const ushort_t* As_ = ((uu >> 5) == 1) ? Al : Ah;                            \
        const ushort_t* Bs_ = ((uu >> 5) == 2) ? Bl : Bh;                            \
        size_t ga = ((size_t)tm*32 + (uu & 31))*4096 + (size_t)tid*8;                \
        size_t gb = ((size_t)tn*32 + (uu & 31))*4096 + (size_t)tid*8;                \
        ushort_t* dA = &lds2[uu & 3][0];                                             \
        ushort_t* dB = &lds2[uu & 3][4096];                                          \
        gll16(As_ + ga,        dA + tid*8);                                          \
        gll16(As_ + ga + 2048, dA + 2048 + tid*8);                                   \
        gll16(Bs_ + gb,        dB + tid*8);                                          \
        gll16(Bs_ + gb + 2048, dB + 2048 + tid*8);                                   \
    }                                                                                \
    __builtin_amdgcn_sched_barrier(0);                                               \
    __builtin_amdgcn_s_setprio(1);                                                   \
    _Pragma("unroll") for (int fm = 0; fm < 4; ++fm)                                 \
        _Pragma("unroll") for (int fn = 0; fn < 4; ++fn)                             \
            acc[fm][fn] = __builtin_amdgcn_mfma_f32_16x16x32_bf16(CA[fm], CB[fn], acc[fm][fn], 0,0,0); \
    __builtin_amdgcn_s_setprio(0);                                                   \
    asm volatile("s_waitcnt lgkmcnt(0)" ::: "memory");                               \
    __builtin_amdgcn_sched_barrier(0);                                               \
    VMASM;                                                                           \
    asm volatile("s_barrier" ::: "memory");                                          \
  }

__global__ __launch_bounds__(256, 2) void k_gemm_sgtg(
    const ushort_t* __restrict__ Ah, const ushort_t* __restrict__ Al,
    const ushort_t* __restrict__ Bh, const ushort_t* __restrict__ Bl,
    const float* __restrict__ bs2,
    float* __restrict__ sgtg)
{
    __shared__ __align__(16) ushort_t lds2[4][8192];   // 64 KiB
    const int tid  = threadIdx.x;
    const int lane = tid & 63;
    const int wid  = tid >> 6;
    const int wr   = wid >> 1;
    const int wc   = wid & 1;
    const int l15  = lane & 15;
    const int lq   = lane >> 4;
    const int bid  = (int)blockIdx.x;
    const int v    = (bid & 7)*64 + (bid >> 3);
    const int tm   = v >> 2;          // 0..127
    const int tn   = v & 3;           // 0..3

    f32x4 acc[4][4];
#pragma unroll
    for (int fn = 0; fn < 4; ++fn) {
        float bv = bs2[tn*128 + wc*64 + fn*16 + l15];
#pragma unroll
        for (int fm = 0; fm < 4; ++fm) {
            acc[fm][fn][0]=bv; acc[fm][fn][1]=bv; acc[fm][fn][2]=bv; acc[fm][fn][3]=bv;
        }
    }

    int aoff[4], boff[4];
#pragma unroll
    for (int f = 0; f < 4; ++f) {
        aoff[f] = (lq*128 + wr*64 + f*16 + l15) * 8;
        boff[f] = (lq*128 + wc*64 + f*16 + l15) * 8;
    }

    short8 a0[4], b0[4], a1[4], b1[4];

#pragma unroll
    for (int u0 = 0; u0 < 3; ++u0) {
        size_t ga = ((size_t)tm*32 + u0)*4096 + (size_t)tid*8;
        size_t gb = ((size_t)tn*32 + u0)*4096 + (size_t)tid*8;
        gll16(Ah + ga,        &lds2[u0][0]    + tid*8);
        gll16(Ah + ga + 2048, &lds2[u0][2048] + tid*8);
        gll16(Bh + gb,        &lds2[u0][4096] + tid*8);
        gll16(Bh + gb + 2048, &lds2[u0][6144] + tid*8);
    }
    asm volatile("s_waitcnt vmcnt(4)" ::: "memory");
    asm volatile("s_barrier" ::: "memory");
#pragma unroll
    for (int f = 0; f < 4; ++f) a0[f] = *(const short8*)&lds2[0][aoff[f]];
#pragma unroll
    for (int f = 0; f < 4; ++f) b0[f] = *(const short8*)&lds2[0][4096 + boff[f]];
    asm volatile("s_waitcnt lgkmcnt(0)" ::: "memory");
    __builtin_amdgcn_sched_barrier(0);

    for (int t = 0; t < 92; t += 2) {
        SSTEP(t,   a0, b0, a1, b1, 1, 1, asm volatile("s_waitcnt vmcnt(4)" ::: "memory"));
        SSTEP(t+1, a1, b1, a0, b0, 1, 1, asm volatile("s_waitcnt vmcnt(4)" ::: "memory"));
    }
    SSTEP(92, a0, b0, a1, b1, 1, 1, asm volatile("s_waitcnt vmcnt(4)" ::: "memory"));
    SSTEP(93, a1, b1, a0, b0, 1, 0, asm volatile("s_waitcnt vmcnt(0)" ::: "memory"));
    SSTEP(94, a0, b0, a1, b1, 1, 0, ((void)0));
    SSTEP(95, a1, b1, a0, b0, 0, 0, ((void)0));

#pragma unroll
    for (int fm = 0; fm < 4; ++fm) {
        int row0 = tm*128 + wr*64 + fm*16 + lq*4;
#pragma unroll
        for (int fn = 0; fn < 4; ++fn) {
            int n = tn*128 + wc*64 + fn*16 + l15;
#pragma unroll
            for (int r = 0; r < 4; ++r) {
                int row = row0 + r;
                float vv = acc[fm][fn][r];
                vv = vv > 0.f ? vv : 0.01f*vv;
                sgtg[(size_t)row*512 + n] = vv;
            }
        }
    }
}

// ---------- final: row dots, threshold decision, gated writeback ----------
__global__ __launch_bounds__(256) void k_final(
    const float* __restrict__ sgtg,
    const float* __restrict__ h0, const float* __restrict__ c0,
    const float* __restrict__ cum,
    const float* __restrict__ W_so, const float* __restrict__ b_so,
    const float* __restrict__ W_to, const float* __restrict__ b_to,
    float* __restrict__ outH, float* __restrict__ outC,
    float* __restrict__ outCum, float* __restrict__ outDelta, float* __restrict__ outProb)
{
    int w = threadIdx.x >> 6;
    int lane = threadIdx.x & 63;
    int b = blockIdx.x * 4 + w;
    const float* row = sgtg + (size_t)b * 512;
    float so = 0.f, to = 0.f;
#pragma unroll
    for (int u = 0; u < 4; ++u) {
        int c = lane + 64 * u;
        so = fmaf(row[c], W_so[c], so);
        to = fmaf(row[256 + c], W_to[c], to);
    }
#pragma unroll
    for (int off = 32; off; off >>= 1) {
        so += __shfl_down(so, off);
        to += __shfl_down(to, off);
    }
    so = __shfl(so, 0);
    to = __shfl(to, 0);
    float delta = sigm(so + b_so[0]);
    float thr   = sigm(to + b_to[0]);
    float cu = cum[b];
    float prob = cu + fminf(delta, 1.0f - cu);
    float hard = (prob > thr) ? 1.0f : 0.0f;
    if (lane == 0) {
        outDelta[b] = delta;
        outProb[b]  = prob;
        outCum[b]   = (1.0f - hard) * prob;
    }
    if (hard == 0.0f) {
#pragma unroll
        for (int u = 0; u < 8; ++u) {
            size_t idx = (size_t)b * 512 + lane + 64 * u;
            outH[idx] = h0[idx];
            outC[idx] = c0[idx];
        }
    }
}

extern "C" void kernel_launch(void* const* d_in, const int* in_sizes, int n_in,
                              void* d_out, int out_size, void* d_ws, size_t ws_size,
                              hipStream_t stream)
{
    const float* x    = (const float*)d_in[0];
    const float* h0   = (const float*)d_in[1];
    const float* c0   = (const float*)d_in[2];
    const float* cum  = (const float*)d_in[3];
    const float* W_ih = (const float*)d_in[4];
    const float* W_hh = (const float*)d_in[5];
    const float* b_ih = (const float*)d_in[6];
    const float* b_hh = (const float*)d_in[7];
    const float* W_sp = (const float*)d_in[8];
    const float* b_sp = (const float*)d_in[9];
    const float* W_sc = (const float*)d_in[10];
    const float* b_sc = (const float*)d_in[11];
    const float* W_so = (const float*)d_in[12];
    const float* b_so = (const float*)d_in[13];
    const float* W_tp = (const float*)d_in[14];
    const float* b_tp = (const float*)d_in[15];
    const float* W_to = (const float*)d_in[16];
    const float* b_to = (const float*)d_in[17];

    float* out      = (float*)d_out;
    float* outH     = out;
    float* outC     = out + (size_t)BB * HH;
    float* outCum   = out + (size_t)2 * BB * HH;
    float* outDelta = outCum + BB;
    float* outProb  = outDelta + BB;

    char* w = (char*)d_ws;
    ushort_t* A1h = (ushort_t*)(w);                       // 33,554,432 B
    ushort_t* A1l = (ushort_t*)(w + 33554432ull);         // 33,554,432 B
    ushort_t* A2h = (ushort_t*)(w + 67108864ull);         // 33,554,432 B
    ushort_t* A2l = (ushort_t*)(w + 100663296ull);        // 33,554,432 B
    ushort_t* B1h = (ushort_t*)(w + 134217728ull);        //  4,194,304 B
    ushort_t* B1l = (ushort_t*)(w + 138412032ull);        //  4,194,304 B
    ushort_t* B2h = (ushort_t*)(w + 142606336ull);        //  1,048,576 B
    ushort_t* B2l = (ushort_t*)(w + 143654912ull);        //  1,048,576 B
    float*    bgp = (float*)(w + 144703488ull);           //      8,192 B
    float*    bs2 = (float*)(w + 144711680ull);           //      2,048 B
    float*    sgtg = (float*)A1h;   // alias: A1 dead after k_gemm_gates

    k_prep_all<<<13568, 256, 0, stream>>>(x, h0, c0, W_ih, W_hh, b_ih, b_hh,
                                          W_sp, W_sc, W_tp, b_sp, b_sc, b_tp,
                                          A1h, A1l, A2h, A2l, B1h, B1l, B2h, B2l,
                                          bgp, bs2);
    k_gemm_gates<<<512, 512, 0, stream>>>(A1h, A1l, B1h, B1l, bgp, c0,
                                          outH, outC, A2h, A2l);
    k_gemm_sgtg<<<512, 256, 0, stream>>>(A2h, A2l, B2h, B2l, bs2, sgtg);
    k_final<<<4096, 256, 0, stream>>>(sgtg, h0, c0, cum, W_so, b_so, W_to, b_to,
                                      outH, outC, outCum, outDelta, outProb);
}

// Round 10
// 334.098 us; speedup vs baseline: 1.1480x; 1.0170x over previous
//
#include <hip/hip_runtime.h>
#include <math.h>

#define BB 16384
#define HH 512

typedef short short8 __attribute__((ext_vector_type(8)));
typedef float f32x4 __attribute__((ext_vector_type(4)));
typedef unsigned short ushort_t;

__device__ __forceinline__ float sigm(float v){ return 1.0f/(1.0f+expf(-v)); }

__device__ __forceinline__ unsigned short f2bf(float f){
    unsigned int u = __float_as_uint(f);
    u = u + 0x7FFFu + ((u>>16)&1u);
    return (unsigned short)(u>>16);
}
__device__ __forceinline__ float bf2f(unsigned short h){
    return __uint_as_float(((unsigned int)h)<<16);
}
__device__ __forceinline__ void gll16(const void* g, void* l){
    __builtin_amdgcn_global_load_lds((const __attribute__((address_space(1))) void*)g,
                                     (__attribute__((address_space(3))) void*)l, 16, 0, 0);
}
__device__ __forceinline__ void split_store(float v, ushort_t* ph, ushort_t* pl, int j){
    unsigned short h = f2bf(v);
    unsigned short l = f2bf(v - bf2f(h));
    ph[j] = h; pl[j] = l;
}

// ---------------- merged prepass (round-5 layouts) ----------------
__global__ void k_prep_all(
    const float* __restrict__ x, const float* __restrict__ h0, const float* __restrict__ c0,
    const float* __restrict__ W_ih, const float* __restrict__ W_hh,
    const float* __restrict__ b_ih, const float* __restrict__ b_hh,
    const float* __restrict__ W_sp, const float* __restrict__ W_sc, const float* __restrict__ W_tp,
    const float* __restrict__ b_sp, const float* __restrict__ b_sc, const float* __restrict__ b_tp,
    ushort_t* __restrict__ A1h, ushort_t* __restrict__ A1l,
    ushort_t* __restrict__ A2h, ushort_t* __restrict__ A2l,
    ushort_t* __restrict__ B1h, ushort_t* __restrict__ B1l,
    ushort_t* __restrict__ B2h, ushort_t* __restrict__ B2l,
    float* __restrict__ bgp, float* __restrict__ bs2)
{
    int bid = blockIdx.x;
    if (bid < 8192) {
        int u = bid*256 + threadIdx.x;
        int r  = u & 255;
        int c  = (u >> 8) & 3;
        int kt = (u >> 10) & 31;
        int tm = u >> 15;
        int row = tm*256 + r;
        int k0 = kt*32 + c*8;
        const float* src = (k0 < 512) ? (x + (size_t)row*512 + k0)
                                      : (h0 + (size_t)row*512 + (k0-512));
        float4 v0 = *(const float4*)(src);
        float4 v1 = *(const float4*)(src+4);
        float vv[8] = {v0.x,v0.y,v0.z,v0.w,v1.x,v1.y,v1.z,v1.w};
        size_t off = (size_t)u * 8;
#pragma unroll
        for (int j=0;j<8;++j) split_store(vv[j], A1h+off, A1l+off, j);
    } else if (bid < 12288) {
        int u = (bid-8192)*256 + threadIdx.x;
        int r  = u & 127;
        int c  = (u >> 7) & 3;
        int tk = (u >> 9) & 15;
        int tm = u >> 13;
        int row = tm*128 + r;
        int k0 = tk*32 + c*8;
        const float* src = c0 + (size_t)row*512 + k0;
        float4 v0 = *(const float4*)(src);
        float4 v1 = *(const float4*)(src+4);
        float vv[8] = {v0.x,v0.y,v0.z,v0.w,v1.x,v1.y,v1.z,v1.w};
        size_t off = ((size_t)tm*32 + tk)*4096 + (size_t)(c*128 + r)*8;
#pragma unroll
        for (int j=0;j<8;++j) split_store(vv[j], A2h+off, A2l+off, j);
    } else if (bid < 13312) {
        int u = (bid-12288)*256 + threadIdx.x;
        int r  = u & 255;
        int c  = (u >> 8) & 3;
        int kt = (u >> 10) & 31;
        int tn = u >> 15;
        int g = (r>>4)&3;
        int h = tn*64 + (r>>6)*16 + (r&15);
        int wrow = g*512 + h;
        int k0 = kt*32 + c*8;
        const float* src = (k0 < 512) ? (W_ih + (size_t)wrow*512 + k0)
                                      : (W_hh + (size_t)wrow*512 + (k0-512));
        float4 v0 = *(const float4*)(src);
        float4 v1 = *(const float4*)(src+4);
        float vv[8] = {v0.x,v0.y,v0.z,v0.w,v1.x,v1.y,v1.z,v1.w};
        size_t off = (size_t)u * 8;
#pragma unroll
        for (int j=0;j<8;++j) split_store(vv[j], B1h+off, B1l+off, j);
        if (kt == 0 && c == 0) bgp[tn*256 + r] = b_ih[wrow] + b_hh[wrow];
    } else {
        int u = (bid-13312)*256 + threadIdx.x;
        int r  = u & 127;
        int c  = (u >> 7) & 3;
        int tk = (u >> 9) & 31;
        int tn = u >> 14;
        int n = tn*128 + r;
        int k0 = tk*32 + c*8;
        float vv[8];
        if (n < 256) {
            const float* src = (k0 < 512) ? (W_sp + (size_t)n*512 + k0)
                                          : (W_sc + (size_t)n*512 + (k0-512));
            float4 v0 = *(const float4*)(src);
            float4 v1 = *(const float4*)(src+4);
            vv[0]=v0.x; vv[1]=v0.y; vv[2]=v0.z; vv[3]=v0.w;
            vv[4]=v1.x; vv[5]=v1.y; vv[6]=v1.z; vv[7]=v1.w;
        } else if (k0 < 512) {
            const float* src = W_tp + (size_t)(n-256)*512 + k0;
            float4 v0 = *(const float4*)(src);
            float4 v1 = *(const float4*)(src+4);
            vv[0]=v0.x; vv[1]=v0.y; vv[2]=v0.z; vv[3]=v0.w;
            vv[4]=v1.x; vv[5]=v1.y; vv[6]=v1.z; vv[7]=v1.w;
        } else {
#pragma unroll
            for (int j=0;j<8;++j) vv[j] = 0.0f;
        }
        size_t off = (size_t)u * 8;
#pragma unroll
        for (int j=0;j<8;++j) split_store(vv[j], B2h+off, B2l+off, j);
        if (tk == 0 && c == 0) bs2[n] = (n < 256) ? (b_sp[n] + b_sc[n]) : b_tp[n-256];
    }
}

// ---------- GEMM1: gates, 256x256, K''=3072, ping-pong, NO scheduling pins ----------
// Step T: read frags T+1, stage T+3, MFMA on regs of T; counted vmcnt; barrier.
// Compiler is free to interleave ds_read issue with MFMA and emit counted lgkmcnt.
#define GSTEP(T, CA, CB, NA, NB, DO_READS, DO_STAGE, VMASM)                          \
  {                                                                                  \
    if (DO_READS) {                                                                  \
        const ushort_t* bufA1 = &lds[((T)+1) & 3][0];                                \
        const ushort_t* bufB1 = &lds[((T)+1) & 3][8192];                             \
        _Pragma("unroll") for (int f = 0; f < 8; ++f)                                \
            NA[f] = *(const short8*)&bufA1[aoff[f]];                                 \
        _Pragma("unroll") for (int f = 0; f < 4; ++f)                                \
            NB[f] = *(const short8*)&bufB1[boff[f]];                                 \
    }                                                                                \
    if (DO_STAGE) {                                                                  \
        const int uu = (T) + 3;                                                      \
        const ushort_t* As_ = ((uu >> 5) == 1) ? Al : Ah;                            \
        const ushort_t* Bs_ = ((uu >> 5) == 2) ? Bl : Bh;                            \
        size_t ga = ((size_t)tm*32 + (uu & 31))*8192 + (size_t)tid*8;                \
        size_t gb = ((size_t)tn*32 + (uu & 31))*8192 + (size_t)tid*8;                \
        ushort_t* dA = &lds[uu & 3][0];                                              \
        ushort_t* dB = &lds[uu & 3][8192];                                           \
        gll16(As_ + ga,        dA + tid*8);                                          \
        gll16(As_ + ga + 4096, dA + 4096 + tid*8);                                   \
        gll16(Bs_ + gb,        dB + tid*8);                                          \
        gll16(Bs_ + gb + 4096, dB + 4096 + tid*8);                                   \
    }                                                                                \
    _Pragma("unroll") for (int fm = 0; fm < 8; ++fm)                                 \
        _Pragma("unroll") for (int fn = 0; fn < 4; ++fn)                             \
            acc[fm][fn] = __builtin_amdgcn_mfma_f32_16x16x32_bf16(CA[fm], CB[fn], acc[fm][fn], 0,0,0); \
    VMASM;                                                                           \
    asm volatile("s_barrier" ::: "memory");                                          \
  }

__global__ __launch_bounds__(512, 2) void k_gemm_gates(
    const ushort_t* __restrict__ Ah, const ushort_t* __restrict__ Al,
    const ushort_t* __restrict__ Bh, const ushort_t* __restrict__ Bl,
    const float* __restrict__ bgp, const float* __restrict__ c0,
    float* __restrict__ outH, float* __restrict__ outC,
    ushort_t* __restrict__ A2h, ushort_t* __restrict__ A2l)
{
    __shared__ __align__(16) ushort_t lds[4][16384];   // 128 KiB
    const int tid  = threadIdx.x;
    const int lane = tid & 63;
    const int wid  = tid >> 6;
    const int wr   = wid >> 2;        // 0..1
    const int wc   = wid & 3;         // 0..3
    const int l15  = lane & 15;
    const int lq   = lane >> 4;
    const int bid  = (int)blockIdx.x;
    const int v    = (bid & 7)*64 + (bid >> 3);   // XCD swizzle
    const int tm   = v >> 3;          // 0..63
    const int tn   = v & 7;           // 0..7

    f32x4 acc[8][4];
#pragma unroll
    for (int fn = 0; fn < 4; ++fn) {
        float bv = bgp[tn*256 + wc*64 + fn*16 + l15];
#pragma unroll
        for (int fm = 0; fm < 8; ++fm) {
            acc[fm][fn][0]=bv; acc[fm][fn][1]=bv; acc[fm][fn][2]=bv; acc[fm][fn][3]=bv;
        }
    }

    int aoff[8], boff[4];
#pragma unroll
    for (int f = 0; f < 8; ++f) aoff[f] = (lq*256 + wr*128 + f*16 + l15) * 8;
#pragma unroll
    for (int f = 0; f < 4; ++f) boff[f] = (lq*256 + wc*64 + f*16 + l15) * 8;

    short8 a0[8], b0[4], a1[8], b1[4];

    // prologue: stage steps 0,1,2; drain 0,1; preload frags of step 0 into set0
#pragma unroll
    for (int u0 = 0; u0 < 3; ++u0) {
        size_t ga = ((size_t)tm*32 + u0)*8192 + (size_t)tid*8;
        size_t gb = ((size_t)tn*32 + u0)*8192 + (size_t)tid*8;
        gll16(Ah + ga,        &lds[u0][0]     + tid*8);
        gll16(Ah + ga + 4096, &lds[u0][4096]  + tid*8);
        gll16(Bh + gb,        &lds[u0][8192]  + tid*8);
        gll16(Bh + gb + 4096, &lds[u0][12288] + tid*8);
    }
    asm volatile("s_waitcnt vmcnt(4)" ::: "memory");
    asm volatile("s_barrier" ::: "memory");
#pragma unroll
    for (int f = 0; f < 8; ++f) a0[f] = *(const short8*)&lds[0][aoff[f]];
#pragma unroll
    for (int f = 0; f < 4; ++f) b0[f] = *(const short8*)&lds[0][8192 + boff[f]];

    for (int t = 0; t < 92; t += 2) {
        GSTEP(t,   a0, b0, a1, b1, 1, 1, asm volatile("s_waitcnt vmcnt(4)" ::: "memory"));
        GSTEP(t+1, a1, b1, a0, b0, 1, 1, asm volatile("s_waitcnt vmcnt(4)" ::: "memory"));
    }
    GSTEP(92, a0, b0, a1, b1, 1, 1, asm volatile("s_waitcnt vmcnt(4)" ::: "memory"));
    GSTEP(93, a1, b1, a0, b0, 1, 0, asm volatile("s_waitcnt vmcnt(0)" ::: "memory"));
    GSTEP(94, a0, b0, a1, b1, 1, 0, ((void)0));
    GSTEP(95, a1, b1, a0, b0, 0, 0, ((void)0));

    // epilogue: lane holds 4 gates (fn) for rows lq*4+r, col h
    const int h = tn*64 + wc*16 + l15;
#pragma unroll
    for (int fm = 0; fm < 8; ++fm) {
        int row0 = tm*256 + wr*128 + fm*16 + lq*4;
#pragma unroll
        for (int r = 0; r < 4; ++r) {
            int row = row0 + r;
            size_t idx = (size_t)row*512 + h;
            float ig = sigm(acc[fm][0][r]);
            float fg = sigm(acc[fm][1][r]);
            float gg = tanhf(acc[fm][2][r]);
            float og = sigm(acc[fm][3][r]);
            float c1 = fg*c0[idx] + ig*gg;
            float h1 = og*tanhf(c1);
            outC[idx] = c1;
            outH[idx] = h1;
            unsigned short ch = f2bf(c1);
            unsigned short cl = f2bf(c1 - bf2f(ch));
            size_t a2 = ((size_t)(row>>7)*32 + 16 + (h>>5))*4096
                      + (size_t)((((h>>3)&3))*128 + (row&127))*8 + (h&7);
            A2h[a2] = ch;
            A2l[a2] = cl;
        }
    }
}

// ---------- GEMM2: sg|tg, 128x128, K''=3072, ping-pong, NO scheduling pins ----------
#define SSTEP(T, CA, CB, NA, NB, DO_READS, DO_STAGE, VMASM)                          \
  {                                                                                  \
    if (DO_READS) {                                                                  \
        const ushort_t* bufA1 = &lds2[((T)+1) & 3][0];                               \
        const ushort_t* bufB1 = &lds2[((T)+1) & 3][4096];                            \
        _Pragma("unroll") for (int f = 0; f < 4; ++f)                                \
            NA[f] = *(const short8*)&bufA1[aoff[f]];                                 \
        _Pragma("unroll") for (int f = 0; f < 4; ++f)                                \
            NB[f] = *(const short8*)&bufB1[boff[f]];                                 \
    }                                                                                \
    if (DO_STAGE) {                                                                  \
        const int uu = (T) + 3;                                                      \
        const ushort_t* As_ = ((uu >> 5) == 1) ? Al : Ah;                            \
        const ushort_t* Bs_ = ((uu >> 5) == 2) ? Bl : Bh;                            \
        size_t ga = ((size_t)tm*32 + (uu & 31))*4096 + (size_t)tid*8;                \
        size_t gb = ((size_t)tn*32 + (uu & 31))*4096 + (size_t)tid*8;                \
        ushort_t* dA = &lds2[uu & 3][0];                                             \
        ushort_t* dB = &lds2[uu & 3][4096];                                          \
        gll16(As_ + ga,        dA + tid*8);                                          \
        gll16(As_ + ga + 2048, dA + 2048 + tid*8);                                   \
        gll16(Bs_ + gb,        dB + tid*8);                                          \
        gll16(Bs_ + gb + 2048, dB + 2048 + tid*8);                                   \
    }                                                                                \
    _Pragma("unroll") for (int fm = 0; fm < 4; ++fm)                                 \
        _Pragma("unroll") for (int fn = 0; fn < 4; ++fn)                             \
            acc[fm][fn] = __builtin_amdgcn_mfma_f32_16x16x32_bf16(CA[fm], CB[fn], acc[fm][fn], 0,0,0); \
    VMASM;                                                                           \
    asm volatile("s_barrier" ::: "memory");                                          \
  }

__global__ __launch_bounds__(256, 2) void k_gemm_sgtg(
    const ushort_t* __restrict__ Ah, const ushort_t* __restrict__ Al,
    const ushort_t* __restrict__ Bh, const ushort_t* __restrict__ Bl,
    const float* __restrict__ bs2,
    float* __restrict__ sgtg)
{
    __shared__ __align__(16) ushort_t lds2[4][8192];   // 64 KiB -> 2 blocks/CU
    const int tid  = threadIdx.x;
    const int lane = tid & 63;
    const int wid  = tid >> 6;
    const int wr   = wid >> 1;
    const int wc   = wid & 1;
    const int l15  = lane & 15;
    const int lq   = lane >> 4;
    const int bid  = (int)blockIdx.x;
    const int v    = (bid & 7)*64 + (bid >> 3);
    const int tm   = v >> 2;          // 0..127
    const int tn   = v & 3;           // 0..3

    f32x4 acc[4][4];
#pragma unroll
    for (int fn = 0; fn < 4; ++fn) {
        float bv = bs2[tn*128 + wc*64 + fn*16 + l15];
#pragma unroll
        for (int fm = 0; fm < 4; ++fm) {
            acc[fm][fn][0]=bv; acc[fm][fn][1]=bv; acc[fm][fn][2]=bv; acc[fm][fn][3]=bv;
        }
    }

    int aoff[4], boff[4];
#pragma unroll
    for (int f = 0; f < 4; ++f) {
        aoff[f] = (lq*128 + wr*64 + f*16 + l15) * 8;
        boff[f] = (lq*128 + wc*64 + f*16 + l15) * 8;
    }

    short8 a0[4], b0[4], a1[4], b1[4];

#pragma unroll
    for (int u0 = 0; u0 < 3; ++u0) {
        size_t ga = ((size_t)tm*32 + u0)*4096 + (size_t)tid*8;
        size_t gb = ((size_t)tn*32 + u0)*4096 + (size_t)tid*8;
        gll16(Ah + ga,        &lds2[u0][0]    + tid*8);
        gll16(Ah + ga + 2048, &lds2[u0][2048] + tid*8);
        gll16(Bh + gb,        &lds2[u0][4096] + tid*8);
        gll16(Bh + gb + 2048, &lds2[u0][6144] + tid*8);
    }
    asm volatile("s_waitcnt vmcnt(4)" ::: "memory");
    asm volatile("s_barrier" ::: "memory");
#pragma unroll
    for (int f = 0; f < 4; ++f) a0[f] = *(const short8*)&lds2[0][aoff[f]];
#pragma unroll
    for (int f = 0; f < 4; ++f) b0[f] = *(const short8*)&lds2[0][4096 + boff[f]];

    for (int t = 0; t < 92; t += 2) {
        SSTEP(t,   a0, b0, a1, b1, 1, 1, asm volatile("s_waitcnt vmcnt(4)" ::: "memory"));
        SSTEP(t+1, a1, b1, a0, b0, 1, 1, asm volatile("s_waitcnt vmcnt(4)" ::: "memory"));
    }
    SSTEP(92, a0, b0, a1, b1, 1, 1, asm volatile("s_waitcnt vmcnt(4)" ::: "memory"));
    SSTEP(93, a1, b1, a0, b0, 1, 0, asm volatile("s_waitcnt vmcnt(0)" ::: "memory"));
    SSTEP(94, a0, b0, a1, b1, 1, 0, ((void)0));
    SSTEP(95, a1, b1, a0, b0, 0, 0, ((void)0));

#pragma unroll
    for (int fm = 0; fm < 4; ++fm) {
        int row0 = tm*128 + wr*64 + fm*16 + lq*4;
#pragma unroll
        for (int fn = 0; fn < 4; ++fn) {
            int n = tn*128 + wc*64 + fn*16 + l15;
#pragma unroll
            for (int r = 0; r < 4; ++r) {
                int row = row0 + r;
                float vv = acc[fm][fn][r];
                vv = vv > 0.f ? vv : 0.01f*vv;
                sgtg[(size_t)row*512 + n] = vv;
            }
        }
    }
}

// ---------- final: row dots, threshold decision, gated writeback ----------
__global__ __launch_bounds__(256) void k_final(
    const float* __restrict__ sgtg,
    const float* __restrict__ h0, const float* __restrict__ c0,
    const float* __restrict__ cum,
    const float* __restrict__ W_so, const float* __restrict__ b_so,
    const float* __restrict__ W_to, const float* __restrict__ b_to,
    float* __restrict__ outH, float* __restrict__ outC,
    float* __restrict__ outCum, float* __restrict__ outDelta, float* __restrict__ outProb)
{
    int w = threadIdx.x >> 6;
    int lane = threadIdx.x & 63;
    int b = blockIdx.x * 4 + w;
    const float* row = sgtg + (size_t)b * 512;
    float so = 0.f, to = 0.f;
#pragma unroll
    for (int u = 0; u < 4; ++u) {
        int c = lane + 64 * u;
        so = fmaf(row[c], W_so[c], so);
        to = fmaf(row[256 + c], W_to[c], to);
    }
#pragma unroll
    for (int off = 32; off; off >>= 1) {
        so += __shfl_down(so, off);
        to += __shfl_down(to, off);
    }
    so = __shfl(so, 0);
    to = __shfl(to, 0);
    float delta = sigm(so + b_so[0]);
    float thr   = sigm(to + b_to[0]);
    float cu = cum[b];
    float prob = cu + fminf(delta, 1.0f - cu);
    float hard = (prob > thr) ? 1.0f : 0.0f;
    if (lane == 0) {
        outDelta[b] = delta;
        outProb[b]  = prob;
        outCum[b]   = (1.0f - hard) * prob;
    }
    if (hard == 0.0f) {
#pragma unroll
        for (int u = 0; u < 8; ++u) {
            size_t idx = (size_t)b * 512 + lane + 64 * u;
            outH[idx] = h0[idx];
            outC[idx] = c0[idx];
        }
    }
}

extern "C" void kernel_launch(void* const* d_in, const int* in_sizes, int n_in,
                              void* d_out, int out_size, void* d_ws, size_t ws_size,
                              hipStream_t stream)
{
    const float* x    = (const float*)d_in[0];
    const float* h0   = (const float*)d_in[1];
    const float* c0   = (const float*)d_in[2];
    const float* cum  = (const float*)d_in[3];
    const float* W_ih = (const float*)d_in[4];
    const float* W_hh = (const float*)d_in[5];
    const float* b_ih = (const float*)d_in[6];
    const float* b_hh = (const float*)d_in[7];
    const float* W_sp = (const float*)d_in[8];
    const float* b_sp = (const float*)d_in[9];
    const float* W_sc = (const float*)d_in[10];
    const float* b_sc = (const float*)d_in[11];
    const float* W_so = (const float*)d_in[12];
    const float* b_so = (const float*)d_in[13];
    const float* W_tp = (const float*)d_in[14];
    const float* b_tp = (const float*)d_in[15];
    const float* W_to = (const float*)d_in[16];
    const float* b_to = (const float*)d_in[17];

    float* out      = (float*)d_out;
    float* outH     = out;
    float* outC     = out + (size_t)BB * HH;
    float* outCum   = out + (size_t)2 * BB * HH;
    float* outDelta = outCum + BB;
    float* outProb  = outDelta + BB;

    char* w = (char*)d_ws;
    ushort_t* A1h = (ushort_t*)(w);                       // 33,554,432 B
    ushort_t* A1l = (ushort_t*)(w + 33554432ull);         // 33,554,432 B
    ushort_t* A2h = (ushort_t*)(w + 67108864ull);         // 33,554,432 B
    ushort_t* A2l = (ushort_t*)(w + 100663296ull);        // 33,554,432 B
    ushort_t* B1h = (ushort_t*)(w + 134217728ull);        //  4,194,304 B
    ushort_t* B1l = (ushort_t*)(w + 138412032ull);        //  4,194,304 B
    ushort_t* B2h = (ushort_t*)(w + 142606336ull);        //  1,048,576 B
    ushort_t* B2l = (ushort_t*)(w + 143654912ull);        //  1,048,576 B
    float*    bgp = (float*)(w + 144703488ull);           //      8,192 B
    float*    bs2 = (float*)(w + 144711680ull);           //      2,048 B
    float*    sgtg = (float*)A1h;   // alias: A1 dead after k_gemm_gates

    k_prep_all<<<13568, 256, 0, stream>>>(x, h0, c0, W_ih, W_hh, b_ih, b_hh,
                                          W_sp, W_sc, W_tp, b_sp, b_sc, b_tp,
                                          A1h, A1l, A2h, A2l, B1h, B1l, B2h, B2l,
                                          bgp, bs2);
    k_gemm_gates<<<512, 512, 0, stream>>>(A1h, A1l, B1h, B1l, bgp, c0,
                                          outH, outC, A2h, A2l);
    k_gemm_sgtg<<<512, 256, 0, stream>>>(A2h, A2l, B2h, B2l, bs2, sgtg);
    k_final<<<4096, 256, 0, stream>>>(sgtg, h0, c0, cum, W_so, b_so, W_to, b_to,
                                      outH, outC, outCum, outDelta, outProb);
}